// Round 17
// baseline (3498.621 us; speedup 1.0000x reference)
//
#include <hip/hip_runtime.h>
#include <cstdint>

#define CDIV(a,b) (((a)+(b)-1)/(b))

typedef __bf16 bf16x8 __attribute__((ext_vector_type(8)));
typedef float  f32x4  __attribute__((ext_vector_type(4)));

__device__ __forceinline__ float bf2f(unsigned short u) {
    unsigned v = ((unsigned)u) << 16;
    float f; __builtin_memcpy(&f, &v, 4); return f;
}
__device__ __forceinline__ unsigned short f2bf(float f) {
    unsigned u; __builtin_memcpy(&u, &f, 4);
    u += 0x7fffu + ((u >> 16) & 1u);
    return (unsigned short)(u >> 16);
}
__device__ __forceinline__ float fsig(float x) { return 1.f / (1.f + __expf(-x)); }
__device__ __forceinline__ float ftanh(float x) { return 2.f * fsig(2.f * x) - 1.f; }

__device__ __forceinline__ void gld_lds16(const void* g, void* l) {
    __builtin_amdgcn_global_load_lds((__attribute__((address_space(1))) void*)(g),
                                     (__attribute__((address_space(3))) void*)(l), 16, 0, 0);
}

// ---------------- misc small kernels ----------------

__global__ __launch_bounds__(256) void k_zero4(uint4* p, size_t n4) {
    size_t i = (size_t)blockIdx.x * 256 + threadIdx.x;
    if (i < n4) p[i] = make_uint4(0, 0, 0, 0);
}

__global__ __launch_bounds__(256) void k_deg(const int* ei, int* degi, int E) {
    int e = blockIdx.x * 256 + threadIdx.x;
    if (e < E) atomicAdd(&degi[ei[E + e]], 1);
}

__global__ __launch_bounds__(256) void k_dinv(const int* degi, float* dinv, int N) {
    int n = blockIdx.x * 256 + threadIdx.x;
    if (n < N) dinv[n] = rsqrtf((float)degi[n] + 1.f);
}

#define SCAN_B 2048
__global__ __launch_bounds__(256) void k_scan1(const int* in, int* out, int* bsum, int n) {
    __shared__ int ls[256];
    int b = blockIdx.x, t = threadIdx.x;
    int base = b * SCAN_B + t * 8;
    int v[8]; int s = 0;
#pragma unroll
    for (int i = 0; i < 8; ++i) { int idx = base + i; v[i] = (idx < n) ? in[idx] : 0; s += v[i]; }
    ls[t] = s; __syncthreads();
    for (int off = 1; off < 256; off <<= 1) {
        int x = (t >= off) ? ls[t - off] : 0;
        __syncthreads();
        ls[t] += x;
        __syncthreads();
    }
    int ex = ls[t] - s;
    if (t == 255) bsum[b] = ls[255];
    int run = ex;
#pragma unroll
    for (int i = 0; i < 8; ++i) { int idx = base + i; if (idx < n) out[idx] = run; run += v[i]; }
}
__global__ void k_scan2(int* bsum, int nb) {
    if (threadIdx.x == 0) {
        int acc = 0;
        for (int b = 0; b < nb; ++b) { int v = bsum[b]; bsum[b] = acc; acc += v; }
    }
}
__global__ __launch_bounds__(256) void k_scan3(int* rowp, int* curs, const int* bsum, int n) {
    int i = blockIdx.x * 256 + threadIdx.x;
    if (i < n) { int v = rowp[i] + bsum[i / SCAN_B]; rowp[i] = v; curs[i] = v; }
}
__global__ __launch_bounds__(256) void k_fill(const int* ei, int* curs, int* csr, int E) {
    int e = blockIdx.x * 256 + threadIdx.x;
    if (e < E) { int d = ei[E + e]; int pos = atomicAdd(&curs[d], 1); csr[pos] = ei[e]; }
}

__global__ __launch_bounds__(256) void k_xconv(const float* x, unsigned short* xb, int N, int Npad) {
    int idx = blockIdx.x * 256 + threadIdx.x;
    if (idx >= Npad * 64) return;
    int n = idx >> 6, q = idx & 63;
    ushort2 o;
    if (n < N) {
        float2 v = *(const float2*)&x[(size_t)n * 128 + q * 2];
        o = make_ushort2(f2bf(v.x), f2bf(v.y));
    } else o = make_ushort2(0, 0);
    *(ushort2*)&xb[(size_t)n * 128 + q * 2] = o;
}

__global__ __launch_bounds__(256) void k_packT(const float* W, unsigned short* BT, int K, int Nout) {
    int idx = blockIdx.x * 256 + threadIdx.x;
    if (idx >= K * Nout) return;
    int o = idx / K, k = idx % K;
    BT[idx] = f2bf(W[(size_t)k * Nout + o]);
}

// LSTM weight pack v4: gate-paired, frag-contiguous.
__global__ __launch_bounds__(256) void k_packlstm4(const float* wih, const float* whh, unsigned short* BT) {
    int idx = blockIdx.x * 256 + threadIdx.x;
    if (idx >= 1024 * 384) return;
    int e = idx & 7, u = idx >> 3;
    int l4 = u & 3, l15 = (u >> 2) & 15, ni = (u >> 6) & 1;
    int rest = u >> 7;
    int ks = rest % 12, G = rest / 12;
    int gate = ni * 2 + (l15 >> 3);
    int hid = G * 8 + (l15 & 7);
    int srow = gate * 256 + hid;
    int k = ks * 32 + l4 * 8 + e;
    float v = (k < 128) ? wih[(size_t)srow * 128 + k] : whh[(size_t)srow * 256 + (k - 128)];
    BT[idx] = f2bf(v);
}
__global__ __launch_bounds__(256) void k_packbias4(const float* bih, const float* bhh, float* bias) {
    int c = blockIdx.x * 256 + threadIdx.x;
    if (c >= 1024) return;
    int G = c >> 5, cc = c & 31;
    int ni = cc >> 4, ll = cc & 15;
    int gate = ni * 2 + (ll >> 3);
    int hid = G * 8 + (ll & 7);
    int srow = gate * 256 + hid;
    bias[c] = bih[srow] + bhh[srow];
}

// ---------------- graph propagation (CSR gather, 8 nodes/wave, 2-stage pipeline) ----------------

__global__ __launch_bounds__(256) void k_prop(const unsigned short* __restrict__ X,
                                              const int* __restrict__ rowp, const int* __restrict__ cnt,
                                              const int* __restrict__ csr, const float* __restrict__ dinv,
                                              const float* __restrict__ bias, int relu,
                                              int N, int Npad, unsigned short* __restrict__ OUT) {
    int node = (blockIdx.x * 256 + threadIdx.x) >> 3;
    if (node >= Npad) return;
    const int g = threadIdx.x & 7;
    unsigned short* op = OUT + (size_t)node * 128 + g * 16;
    if (node >= N) {
        *(uint4*)op = make_uint4(0, 0, 0, 0);
        *(uint4*)(op + 8) = make_uint4(0, 0, 0, 0);
        return;
    }
    const int beg = rowp[node], num = cnt[node];
    const float di = dinv[node];
    float a[16];
#pragma unroll
    for (int j = 0; j < 16; ++j) a[j] = 0.f;
    if (num > 0) {
        int s = csr[beg];
        float ws = dinv[s];
        const unsigned short* rp = &X[(size_t)s * 128 + g * 16];
        uint4 qa = *(const uint4*)rp;
        uint4 qb = *(const uint4*)(rp + 8);
        for (int i = 0; i < num; ++i) {
            int sn = (i + 1 < num) ? csr[beg + i + 1] : s;
            float wn = dinv[sn];
            const unsigned short* rn = &X[(size_t)sn * 128 + g * 16];
            uint4 pa = *(const uint4*)rn;
            uint4 pb = *(const uint4*)(rn + 8);
            a[0]  = fmaf(ws, bf2f((unsigned short)(qa.x & 0xffffu)), a[0]);
            a[1]  = fmaf(ws, bf2f((unsigned short)(qa.x >> 16)), a[1]);
            a[2]  = fmaf(ws, bf2f((unsigned short)(qa.y & 0xffffu)), a[2]);
            a[3]  = fmaf(ws, bf2f((unsigned short)(qa.y >> 16)), a[3]);
            a[4]  = fmaf(ws, bf2f((unsigned short)(qa.z & 0xffffu)), a[4]);
            a[5]  = fmaf(ws, bf2f((unsigned short)(qa.z >> 16)), a[5]);
            a[6]  = fmaf(ws, bf2f((unsigned short)(qa.w & 0xffffu)), a[6]);
            a[7]  = fmaf(ws, bf2f((unsigned short)(qa.w >> 16)), a[7]);
            a[8]  = fmaf(ws, bf2f((unsigned short)(qb.x & 0xffffu)), a[8]);
            a[9]  = fmaf(ws, bf2f((unsigned short)(qb.x >> 16)), a[9]);
            a[10] = fmaf(ws, bf2f((unsigned short)(qb.y & 0xffffu)), a[10]);
            a[11] = fmaf(ws, bf2f((unsigned short)(qb.y >> 16)), a[11]);
            a[12] = fmaf(ws, bf2f((unsigned short)(qb.z & 0xffffu)), a[12]);
            a[13] = fmaf(ws, bf2f((unsigned short)(qb.z >> 16)), a[13]);
            a[14] = fmaf(ws, bf2f((unsigned short)(qb.w & 0xffffu)), a[14]);
            a[15] = fmaf(ws, bf2f((unsigned short)(qb.w >> 16)), a[15]);
            s = sn; ws = wn; qa = pa; qb = pb;
        }
    }
    const unsigned short* xp = &X[(size_t)node * 128 + g * 16];
    uint4 xa = *(const uint4*)xp;
    uint4 xb4 = *(const uint4*)(xp + 8);
    const float dd = di * di;
    float o[16];
    o[0]  = di * a[0]  + dd * bf2f((unsigned short)(xa.x & 0xffffu));
    o[1]  = di * a[1]  + dd * bf2f((unsigned short)(xa.x >> 16));
    o[2]  = di * a[2]  + dd * bf2f((unsigned short)(xa.y & 0xffffu));
    o[3]  = di * a[3]  + dd * bf2f((unsigned short)(xa.y >> 16));
    o[4]  = di * a[4]  + dd * bf2f((unsigned short)(xa.z & 0xffffu));
    o[5]  = di * a[5]  + dd * bf2f((unsigned short)(xa.z >> 16));
    o[6]  = di * a[6]  + dd * bf2f((unsigned short)(xa.w & 0xffffu));
    o[7]  = di * a[7]  + dd * bf2f((unsigned short)(xa.w >> 16));
    o[8]  = di * a[8]  + dd * bf2f((unsigned short)(xb4.x & 0xffffu));
    o[9]  = di * a[9]  + dd * bf2f((unsigned short)(xb4.x >> 16));
    o[10] = di * a[10] + dd * bf2f((unsigned short)(xb4.y & 0xffffu));
    o[11] = di * a[11] + dd * bf2f((unsigned short)(xb4.y >> 16));
    o[12] = di * a[12] + dd * bf2f((unsigned short)(xb4.z & 0xffffu));
    o[13] = di * a[13] + dd * bf2f((unsigned short)(xb4.z >> 16));
    o[14] = di * a[14] + dd * bf2f((unsigned short)(xb4.w & 0xffffu));
    o[15] = di * a[15] + dd * bf2f((unsigned short)(xb4.w >> 16));
    if (bias) {
        const float* bp = bias + g * 16;
#pragma unroll
        for (int j = 0; j < 16; ++j) o[j] += bp[j];
    }
    if (relu) {
#pragma unroll
        for (int j = 0; j < 16; ++j) o[j] = fmaxf(o[j], 0.f);
    }
    uint4 r0, r1;
    r0.x = (unsigned)f2bf(o[0])  | ((unsigned)f2bf(o[1])  << 16);
    r0.y = (unsigned)f2bf(o[2])  | ((unsigned)f2bf(o[3])  << 16);
    r0.z = (unsigned)f2bf(o[4])  | ((unsigned)f2bf(o[5])  << 16);
    r0.w = (unsigned)f2bf(o[6])  | ((unsigned)f2bf(o[7])  << 16);
    r1.x = (unsigned)f2bf(o[8])  | ((unsigned)f2bf(o[9])  << 16);
    r1.y = (unsigned)f2bf(o[10]) | ((unsigned)f2bf(o[11]) << 16);
    r1.z = (unsigned)f2bf(o[12]) | ((unsigned)f2bf(o[13]) << 16);
    r1.w = (unsigned)f2bf(o[14]) | ((unsigned)f2bf(o[15]) << 16);
    *(uint4*)op = r0;
    *(uint4*)(op + 8) = r1;
}

// ---------------- batchnorm stats / apply ----------------

__global__ __launch_bounds__(256) void k_stats(const unsigned short* __restrict__ X, int rows, float* part) {
    __shared__ float ls[512];
    int t = threadIdx.x, b = blockIdx.x;
    int ch = t & 127, half = t >> 7;
    float s = 0.f, s2 = 0.f;
    for (int r = b * 2 + half; r < rows; r += 512) {
        float v = bf2f(X[(size_t)r * 128 + ch]);
        s += v; s2 += v * v;
    }
    ls[t] = s; ls[256 + t] = s2;
    __syncthreads();
    if (t < 128) {
        part[b * 256 + t] = ls[t] + ls[t + 128];
        part[b * 256 + 128 + t] = ls[256 + t] + ls[256 + t + 128];
    }
}
__global__ void k_bnfinal(const float* part, int nb, float rows,
                          const float* gamma, const float* beta, float* bnst) {
    int ch = threadIdx.x;
    if (ch >= 128) return;
    float s = 0.f, s2 = 0.f;
    for (int b = 0; b < nb; ++b) { s += part[b * 256 + ch]; s2 += part[b * 256 + 128 + ch]; }
    float mu = s / rows, var = s2 / rows - mu * mu;
    float sc = gamma[ch] * rsqrtf(var + 1e-5f);
    bnst[ch] = sc;
    bnst[128 + ch] = beta[ch] - mu * sc;
}
__global__ __launch_bounds__(256) void k_apply(const unsigned short* in, const float* bnst,
                                               unsigned short* outv, int N, int Npad) {
    int idx = blockIdx.x * 256 + threadIdx.x;
    if (idx >= Npad * 64) return;
    int n = idx >> 6, q = idx & 63;
    ushort2 o;
    if (n < N) {
        ushort2 v = *(const ushort2*)&in[(size_t)n * 128 + q * 2];
        int c0 = q * 2;
        o = make_ushort2(f2bf(bf2f(v.x) * bnst[c0] + bnst[128 + c0]),
                         f2bf(bf2f(v.y) * bnst[c0 + 1] + bnst[128 + c0 + 1]));
    } else o = make_ushort2(0, 0);
    *(ushort2*)&outv[(size_t)n * 128 + q * 2] = o;
}

// ---------------- GEMM core: 128x128 tile, BK=64, 16x16x32 bf16 MFMA ----------------

template<int GATHER>
__device__ __forceinline__ void gemm_core(
    const unsigned short* __restrict__ A0, int lda0, int K0,
    const unsigned short* __restrict__ A1, int lda1, int Ktot,
    const unsigned short* __restrict__ BT, int ldb,
    const int* __restrict__ gR, const int* __restrict__ gC, int ELr,
    int m0, int c0, unsigned short* sA, unsigned short* sB, f32x4 acc[4][4]) {
    const int tid = threadIdx.x;
    const int wid = tid >> 6, lane = tid & 63;
    const int l15 = lane & 15, l4 = lane >> 4;
    const int wr = (wid >> 1) * 64, wc = (wid & 1) * 64;
    const int crow = lane >> 3;
    const int cslot = (lane & 7) ^ crow;
    const int nK = Ktot >> 6;
    for (int ks = 0; ks < nK; ++ks) {
        const int k0 = ks << 6;
#pragma unroll
        for (int i = 0; i < 4; ++i) {
            const int chunk = wid * 4 + i;
            const int row = chunk * 8 + crow;
            const unsigned short* bs = BT + (size_t)(c0 + row) * ldb + k0 + (cslot << 3);
            gld_lds16(bs, sB + chunk * 512);
            if constexpr (GATHER) {
                int e = m0 + row; if (e >= ELr) e = ELr - 1;
                const int nid = (k0 < K0) ? gR[e] : gC[e];
                const unsigned short* as = A0 + (size_t)nid * lda0 + (k0 & (K0 - 1)) + (lane & 7) * 8;
                *(uint4*)(sA + chunk * 512 + crow * 64 + (((lane & 7) ^ crow) << 3)) = *(const uint4*)as;
            } else {
                const unsigned short* as = (k0 < K0)
                    ? A0 + (size_t)(m0 + row) * lda0 + k0 + (cslot << 3)
                    : A1 + (size_t)(m0 + row) * lda1 + (k0 - K0) + (cslot << 3);
                gld_lds16(as, sA + chunk * 512);
            }
        }
        __syncthreads();
#pragma unroll
        for (int kk = 0; kk < 2; ++kk) {
            const int c8 = kk * 4 + l4;
            const int rs = l15 & 7;
            bf16x8 av[4], bv[4];
#pragma unroll
            for (int i = 0; i < 4; ++i)
                av[i] = *(const bf16x8*)(sA + (wr + i * 16 + l15) * 64 + ((c8 ^ rs) << 3));
#pragma unroll
            for (int i = 0; i < 4; ++i)
                bv[i] = *(const bf16x8*)(sB + (wc + i * 16 + l15) * 64 + ((c8 ^ rs) << 3));
#pragma unroll
            for (int mi = 0; mi < 4; ++mi)
#pragma unroll
                for (int ni = 0; ni < 4; ++ni)
                    acc[mi][ni] = __builtin_amdgcn_mfma_f32_16x16x32_bf16(av[mi], bv[ni], acc[mi][ni], 0, 0, 0);
        }
        __syncthreads();
    }
}

template<int GATHER>
__global__ __launch_bounds__(256) void k_gemm(
    const unsigned short* __restrict__ A0, int lda0, int K0,
    const unsigned short* __restrict__ A1, int lda1, int Ktot,
    const unsigned short* __restrict__ BT, int ldb,
    const int* __restrict__ gR, const int* __restrict__ gC, int ELr,
    const float* __restrict__ bias, int relu,
    unsigned short* __restrict__ C, int ldc, int NT) {
    extern __shared__ char smem[];
    unsigned short* sA = (unsigned short*)smem;
    unsigned short* sB = (unsigned short*)(smem + 16384);
    int mt = blockIdx.x / NT, nt = blockIdx.x % NT;
    int m0 = mt * 128, c0 = nt * 128;
    f32x4 acc[4][4];
#pragma unroll
    for (int a = 0; a < 4; ++a)
#pragma unroll
        for (int b = 0; b < 4; ++b) acc[a][b] = (f32x4){0.f, 0.f, 0.f, 0.f};
    gemm_core<GATHER>(A0, lda0, K0, A1, lda1, Ktot, BT, ldb, gR, gC, ELr, m0, c0, sA, sB, acc);
    const int tid = threadIdx.x;
    const int wid = tid >> 6, lane = tid & 63;
    const int l15 = lane & 15, l4 = lane >> 4;
    const int wr = (wid >> 1) * 64, wc = (wid & 1) * 64;
#pragma unroll
    for (int ni = 0; ni < 4; ++ni) {
        int col = c0 + wc + ni * 16 + l15;
        float bv = bias ? bias[col] : 0.f;
#pragma unroll
        for (int mi = 0; mi < 4; ++mi) {
            int rbase = m0 + wr + mi * 16 + l4 * 4;
#pragma unroll
            for (int j = 0; j < 4; ++j) {
                float v = acc[mi][ni][j] + bv;
                if (relu) v = fmaxf(v, 0.f);
                C[(size_t)(rbase + j) * ldc + col] = f2bf(v);
            }
        }
    }
}

// ---------------- fused bidirectional LSTM v14 ----------------
// r14-verified math/structure, re-tiled to 32-row blocks of 256 threads (4 waves):
// wave owns 8 hid-groups (G = wid*8+p, p 0..7), acc[2][2] per pass, c in regs via 8
// statically-expanded passes. LDS = 8KB xls (sc_ld aliased) + 2x16KB h dbuf = 40KB
// -> up to 4 blocks/CU (16 waves). ks-loops stay unroll-1 (no B-load hoisting).

__global__ __launch_bounds__(256)
void k_lstm_fused(
    const unsigned short* __restrict__ xs,     // [4][Npad][128]
    const unsigned short* __restrict__ BT2f, const unsigned short* __restrict__ BT2b,
    const float* __restrict__ bias2f, const float* __restrict__ bias2b,
    const float* __restrict__ att_w,           // [512]
    float* __restrict__ scores,                // [4][N]
    int N, int Npad) {
    __shared__ char shx[32 * 128 * 2];           // 8KB: xls during GEMM, sc_ld after
    __shared__ unsigned short hbuf[2][32 * 256]; // 2x16KB h dbuf, swizzled
    unsigned short* xls = (unsigned short*)shx;
    float* sc_ld = (float*)shx;                  // [4][32]

    const int tid = threadIdx.x;
    const int wid = tid >> 6, lane = tid & 63;
    const int l15 = lane & 15, l4 = lane >> 4;
    const int rs = l15 & 7;
    const int m0 = blockIdx.x * 32;
    const int loff = (l15 * 4 + l4) * 8;         // frag lane offset (shorts)
    const bool hi = (l15 & 8) != 0;

    float scl[4] = {0.f, 0.f, 0.f, 0.f};         // meaningful for tid<32

#pragma unroll 1
    for (int dir = 0; dir < 2; ++dir) {
        const unsigned short* BT2 = dir ? BT2b : BT2f;
        const float* bias2 = dir ? bias2b : bias2f;
        const float* attw = att_w + dir * 256;
        for (int i = tid; i < 1024; i += 256) ((uint4*)hbuf[0])[i] = make_uint4(0, 0, 0, 0);
        __syncthreads();
        unsigned short* hcur = hbuf[0];
        unsigned short* hnxt = hbuf[1];
        float c0[2][2], c1[2][2], c2[2][2], c3[2][2];
        float c4[2][2], c5[2][2], c6[2][2], c7[2][2];
#pragma unroll
        for (int a = 0; a < 2; ++a) {
            c0[a][0] = 0.f; c0[a][1] = 0.f; c1[a][0] = 0.f; c1[a][1] = 0.f;
            c2[a][0] = 0.f; c2[a][1] = 0.f; c3[a][0] = 0.f; c3[a][1] = 0.f;
            c4[a][0] = 0.f; c4[a][1] = 0.f; c5[a][0] = 0.f; c5[a][1] = 0.f;
            c6[a][0] = 0.f; c6[a][1] = 0.f; c7[a][0] = 0.f; c7[a][1] = 0.f;
        }

#pragma unroll 1
        for (int t = 0; t < 4; ++t) {
            const int lyr = dir ? (3 - t) : t;
            // stage xls: 8 chunks of 1KB (4 rows x 256B), 2 per wave
            {
                const unsigned short* xl = xs + (size_t)lyr * Npad * 128;
#pragma unroll
                for (int i = 0; i < 2; ++i) {
                    int chunk = wid * 2 + i;
                    int row = chunk * 4 + l4;
                    gld_lds16(xl + (size_t)(m0 + row) * 128 + ((l15 ^ (row & 7)) << 3),
                              xls + chunk * 512);
                }
            }
            __syncthreads();   // B1: xls ready; h(t-1) visible

            float scA[2], scB[2];
#pragma unroll
            for (int a = 0; a < 2; ++a) { scA[a] = 0.f; scB[a] = 0.f; }

#define DO_PASS(P, cp)                                                               \
            {                                                                        \
                const int G = wid * 8 + (P);                                         \
                f32x4 acc[2][2];                                                     \
                _Pragma("unroll")                                                    \
                for (int a = 0; a < 2; ++a) {                                        \
                    acc[a][0] = (f32x4){0.f, 0.f, 0.f, 0.f};                         \
                    acc[a][1] = (f32x4){0.f, 0.f, 0.f, 0.f};                         \
                }                                                                    \
                const unsigned short* bpp = BT2 + (size_t)G * 12288 + loff;          \
                _Pragma("unroll 1")                                                  \
                for (int ks = 0; ks < 4; ++ks) {                                     \
                    bf16x8 bv0 = *(const bf16x8*)(bpp + (ks * 2 + 0) * 512);         \
                    bf16x8 bv1 = *(const bf16x8*)(bpp + (ks * 2 + 1) * 512);         \
                    _Pragma("unroll")                                                \
                    for (int mi = 0; mi < 2; ++mi) {                                 \
                        bf16x8 av = *(const bf16x8*)(xls + (mi * 16 + l15) * 128 +   \
                                                     (((ks * 4 + l4) ^ rs) << 3));   \
                        acc[mi][0] = __builtin_amdgcn_mfma_f32_16x16x32_bf16(av, bv0, acc[mi][0], 0, 0, 0); \
                        acc[mi][1] = __builtin_amdgcn_mfma_f32_16x16x32_bf16(av, bv1, acc[mi][1], 0, 0, 0); \
                    }                                                                \
                }                                                                    \
                _Pragma("unroll 1")                                                  \
                for (int ks = 4; ks < 12; ++ks) {                                    \
                    bf16x8 bv0 = *(const bf16x8*)(bpp + (ks * 2 + 0) * 512);         \
                    bf16x8 bv1 = *(const bf16x8*)(bpp + (ks * 2 + 1) * 512);         \
                    _Pragma("unroll")                                                \
                    for (int mi = 0; mi < 2; ++mi) {                                 \
                        bf16x8 av = *(const bf16x8*)(hcur + (mi * 16 + l15) * 256 +  \
                                                     ((((ks - 4) * 4 + l4) ^ rs) << 3)); \
                        acc[mi][0] = __builtin_amdgcn_mfma_f32_16x16x32_bf16(av, bv0, acc[mi][0], 0, 0, 0); \
                        acc[mi][1] = __builtin_amdgcn_mfma_f32_16x16x32_bf16(av, bv1, acc[mi][1], 0, 0, 0); \
                    }                                                                \
                }                                                                    \
                const float bi0 = bias2[G * 32 + l15];                               \
                const float bi1 = bias2[G * 32 + 16 + l15];                          \
                const float aw = attw[G * 8 + (l15 & 7)];                            \
                _Pragma("unroll")                                                    \
                for (int mi = 0; mi < 2; ++mi) {                                     \
                    float a00 = acc[mi][0][0] + bi0, a01 = acc[mi][0][1] + bi0;      \
                    float a02 = acc[mi][0][2] + bi0, a03 = acc[mi][0][3] + bi0;      \
                    float a10 = acc[mi][1][0] + bi1, a11 = acc[mi][1][1] + bi1;      \
                    float a12 = acc[mi][1][2] + bi1, a13 = acc[mi][1][3] + bi1;      \
                    float r0 = __shfl_xor(hi ? a00 : a02, 8);                        \
                    float r1 = __shfl_xor(hi ? a01 : a03, 8);                        \
                    float r2 = __shfl_xor(hi ? a10 : a12, 8);                        \
                    float r3 = __shfl_xor(hi ? a11 : a13, 8);                        \
                    float iA = hi ? r0  : a00,  fA = hi ? a02 : r0;                  \
                    float gA = hi ? r2  : a10,  oA = hi ? a12 : r2;                  \
                    float iB = hi ? r1  : a01,  fB = hi ? a03 : r1;                  \
                    float gB = hi ? r3  : a11,  oB = hi ? a13 : r3;                  \
                    const int rA = mi * 16 + l4 * 4 + (hi ? 2 : 0);                  \
                    {                                                                \
                        float gi = fsig(iA), gf = fsig(fA), gg = ftanh(gA), go = fsig(oA); \
                        float cc = fmaf(gf, cp[mi][0], gi * gg);                     \
                        cp[mi][0] = cc;                                              \
                        float hn = go * ftanh(cc);                                   \
                        scA[mi] = fmaf(hn, aw, scA[mi]);                             \
                        *(unsigned short*)((char*)hnxt + rA * 512 +                  \
                                           ((G ^ (rA & 7)) << 4) + (l15 & 7) * 2) = f2bf(hn); \
                    }                                                                \
                    {                                                                \
                        const int rB = rA + 1;                                       \
                        float gi = fsig(iB), gf = fsig(fB), gg = ftanh(gB), go = fsig(oB); \
                        float cc = fmaf(gf, cp[mi][1], gi * gg);                     \
                        cp[mi][1] = cc;                                              \
                        float hn = go * ftanh(cc);                                   \
                        scB[mi] = fmaf(hn, aw, scB[mi]);                             \
                        *(unsigned short*)((char*)hnxt + rB * 512 +                  \
                                           ((G ^ (rB & 7)) << 4) + (l15 & 7) * 2) = f2bf(hn); \
                    }                                                                \
                }                                                                    \
            }

            DO_PASS(0, c0)
            DO_PASS(1, c1)
            DO_PASS(2, c2)
            DO_PASS(3, c3)
            DO_PASS(4, c4)
            DO_PASS(5, c5)
            DO_PASS(6, c6)
            DO_PASS(7, c7)
#undef DO_PASS

            __syncthreads();   // B2: all xls/h(t-1) reads + hnxt writes done
            // publish per-row score partials into sc_ld (aliases xls - safe now)
#pragma unroll
            for (int mi = 0; mi < 2; ++mi) {
                float sA = scA[mi], sB = scB[mi];
                sA += __shfl_xor(sA, 1); sA += __shfl_xor(sA, 2); sA += __shfl_xor(sA, 4);
                sB += __shfl_xor(sB, 1); sB += __shfl_xor(sB, 2); sB += __shfl_xor(sB, 4);
                if ((l15 & 7) == 0) {
                    int row = mi * 16 + l4 * 4 + (hi ? 2 : 0);
                    sc_ld[wid * 32 + row] = sA;
                    sc_ld[wid * 32 + row + 1] = sB;
                }
            }
            __syncthreads();   // B3: sc visible
            if (tid < 32) {
                float s = 0.f;
#pragma unroll
                for (int w = 0; w < 4; ++w) s += sc_ld[w * 32 + tid];
#pragma unroll
                for (int l = 0; l < 4; ++l) scl[l] += (l == lyr) ? s : 0.f;
            }
            __syncthreads();   // B4: consumption done -> shx free for next staging
            unsigned short* tmp = hcur; hcur = hnxt; hnxt = tmp;
        }
    }
    if (tid < 32) {
        int n = m0 + tid;
        if (n < N) {
#pragma unroll
            for (int l = 0; l < 4; ++l) scores[(size_t)l * N + n] = scl[l];
        }
    }
}

// ---------------- JK pooling + final predictor ----------------

__global__ __launch_bounds__(256) void k_jk(const float* __restrict__ sc, const unsigned short* __restrict__ xs,
                                            unsigned short* __restrict__ jk, int N, int Npad) {
    int gw = (blockIdx.x * 256 + threadIdx.x) >> 6;
    if (gw >= N) return;
    int lane = threadIdx.x & 63;
    float s0 = sc[gw], s1 = sc[N + gw], s2 = sc[2 * N + gw], s3 = sc[3 * N + gw];
    float m = fmaxf(fmaxf(s0, s1), fmaxf(s2, s3));
    float e0 = __expf(s0 - m), e1 = __expf(s1 - m), e2 = __expf(s2 - m), e3 = __expf(s3 - m);
    float inv = 1.f / (e0 + e1 + e2 + e3);
    float a0 = e0 * inv, a1 = e1 * inv, a2 = e2 * inv, a3 = e3 * inv;
    size_t stride = (size_t)Npad * 128;
    const unsigned short* p = xs + (size_t)gw * 128 + lane * 2;
    ushort2 v0 = *(const ushort2*)p;
    ushort2 v1 = *(const ushort2*)(p + stride);
    ushort2 v2 = *(const ushort2*)(p + 2 * stride);
    ushort2 v3 = *(const ushort2*)(p + 3 * stride);
    float r0 = a0 * bf2f(v0.x) + a1 * bf2f(v1.x) + a2 * bf2f(v2.x) + a3 * bf2f(v3.x);
    float r1 = a0 * bf2f(v0.y) + a1 * bf2f(v1.y) + a2 * bf2f(v2.y) + a3 * bf2f(v3.y);
    *(ushort2*)&jk[(size_t)gw * 128 + lane * 2] = make_ushort2(f2bf(r0), f2bf(r1));
}

__global__ __launch_bounds__(256) void k_final(const unsigned short* __restrict__ z1, const float* __restrict__ bnst,
                                               const float* __restrict__ w2, const float* __restrict__ b2,
                                               float* __restrict__ out, int EL) {
    int e = (blockIdx.x * 256 + threadIdx.x) >> 6;
    if (e >= EL) return;
    int lane = threadIdx.x & 63;
    ushort2 z = *(const ushort2*)&z1[(size_t)e * 128 + lane * 2];
    int c0 = lane * 2;
    float y0 = bf2f(z.x) * bnst[c0] + bnst[128 + c0];
    float y1 = bf2f(z.y) * bnst[c0 + 1] + bnst[128 + c0 + 1];
    float p = y0 * w2[c0] + y1 * w2[c0 + 1];
#pragma unroll
    for (int off = 32; off; off >>= 1) p += __shfl_xor(p, off);
    if (lane == 0) out[e] = 1.f / (1.f + __expf(-(p + b2[0])));
}

// ---------------- host ----------------

extern "C" void kernel_launch(void* const* d_in, const int* in_sizes, int n_in,
                              void* d_out, int out_size, void* d_ws, size_t ws_size,
                              hipStream_t stream) {
    const int* ei      = (const int*)d_in[0];
    const float* x     = (const float*)d_in[1];
    const int* eli     = (const int*)d_in[2];
    const float* gcn_w = (const float*)d_in[3];
    const float* gcn_b = (const float*)d_in[4];
    const float* sg_w  = (const float*)d_in[5];
    const float* sg_b  = (const float*)d_in[6];
    const float* bn_g  = (const float*)d_in[7];
    const float* bn_b  = (const float*)d_in[8];
    const float* w_ih_f = (const float*)d_in[9];
    const float* w_hh_f = (const float*)d_in[10];
    const float* b_ih_f = (const float*)d_in[11];
    const float* b_hh_f = (const float*)d_in[12];
    const float* w_ih_b = (const float*)d_in[13];
    const float* w_hh_b = (const float*)d_in[14];
    const float* b_ih_b = (const float*)d_in[15];
    const float* b_hh_b = (const float*)d_in[16];
    const float* att_w = (const float*)d_in[17];
    // d_in[18] = att_b: softmax over layers is shift-invariant -> unused
    const float* p1_w  = (const float*)d_in[19];
    const float* p1_b  = (const float*)d_in[20];
    const float* pbn_g = (const float*)d_in[21];
    const float* pbn_b = (const float*)d_in[22];
    const float* p2_w  = (const float*)d_in[23];
    const float* p2_b  = (const float*)d_in[24];

    const int E = in_sizes[0] / 2;
    const int N = in_sizes[1] / 128;
    const int EL = in_sizes[2] / 2;
    const int Npad = CDIV(N, 128) * 128;
    const int ELpad = CDIV(EL, 128) * 128;
    const size_t NB128 = (size_t)Npad * 128 * 2;

    char* wsp = (char*)d_ws;
    size_t off = 0;
    auto A = [&](size_t b) -> char* {
        char* p = wsp + off;
        off = (off + b + 255) & ~(size_t)255;
        return p;
    };
    // ---- persistent ----
    int* degi = (int*)A((size_t)N * 4);
    float* dinv = (float*)A((size_t)N * 4);
    int* rowp = (int*)A((size_t)N * 4);
    int* curs = (int*)A((size_t)N * 4);
    int* bsum = (int*)A(256 * 4);
    unsigned short* gT   = (unsigned short*)A(128 * 128 * 2);
    unsigned short* sgT  = (unsigned short*)A(3 * 128 * 128 * 2);
    unsigned short* p1T  = (unsigned short*)A(128 * 256 * 2);
    unsigned short* BTf  = (unsigned short*)A(1024 * 384 * 2);
    unsigned short* BTb  = (unsigned short*)A(1024 * 384 * 2);
    float* biasf = (float*)A(1024 * 4);
    float* biasb = (float*)A(1024 * 4);
    float* part = (float*)A(256 * 256 * 4);
    float* bnst = (float*)A(256 * 4);
    float* scores = (float*)A((size_t)4 * N * 4);
    unsigned short* xs = (unsigned short*)A(NB128 * 4);
    // ---- phase-aliased arena ----
    const size_t arena0 = off;
    int* csr = (int*)A((size_t)E * 4);
    unsigned short* xb   = (unsigned short*)A(NB128);
    unsigned short* bufA = (unsigned short*)A(NB128);
    unsigned short* bufB = (unsigned short*)A(NB128);
    const size_t convEnd = off;
    off = arena0;
    unsigned short* jk = (unsigned short*)A((size_t)N * 128 * 2);
    unsigned short* z1 = (unsigned short*)A((size_t)ELpad * 128 * 2);
    const size_t predEnd = off;
    if (convEnd > ws_size || predEnd > ws_size) return;  // workspace too small

    // --- degree, dinv, CSR ---
    k_zero4<<<CDIV((size_t)N * 4, 16 * 256), 256, 0, stream>>>((uint4*)degi, CDIV((size_t)N * 4, 16));
    k_deg<<<CDIV(E, 256), 256, 0, stream>>>(ei, degi, E);
    k_dinv<<<CDIV(N, 256), 256, 0, stream>>>(degi, dinv, N);
    int nb = CDIV(N, SCAN_B);
    k_scan1<<<nb, 256, 0, stream>>>(degi, rowp, bsum, N);
    k_scan2<<<1, 64, 0, stream>>>(bsum, nb);
    k_scan3<<<CDIV(N, 256), 256, 0, stream>>>(rowp, curs, bsum, N);
    k_fill<<<CDIV(E, 256), 256, 0, stream>>>(ei, curs, csr, E);

    // --- convert + weight packs ---
    k_xconv<<<CDIV(Npad * 64, 256), 256, 0, stream>>>(x, xb, N, Npad);
    k_packT<<<CDIV(128 * 128, 256), 256, 0, stream>>>(gcn_w, gT, 128, 128);
    for (int i = 0; i < 3; ++i)
        k_packT<<<CDIV(128 * 128, 256), 256, 0, stream>>>(sg_w + (size_t)i * 128 * 128, sgT + (size_t)i * 128 * 128, 128, 128);
    k_packT<<<CDIV(256 * 128, 256), 256, 0, stream>>>(p1_w, p1T, 256, 128);
    k_packlstm4<<<CDIV(1024 * 384, 256), 256, 0, stream>>>(w_ih_f, w_hh_f, BTf);
    k_packlstm4<<<CDIV(1024 * 384, 256), 256, 0, stream>>>(w_ih_b, w_hh_b, BTb);
    k_packbias4<<<4, 256, 0, stream>>>(b_ih_f, b_hh_f, biasf);
    k_packbias4<<<4, 256, 0, stream>>>(b_ih_b, b_hh_b, biasb);

    const int MT = Npad / 128;
    // --- GCNConv: lin -> prop(+bias,relu) -> BN ---
    k_gemm<0><<<MT, 256, 32768, stream>>>(xb, 128, 128, nullptr, 0, 128, gT, 128,
                                          nullptr, nullptr, 0, nullptr, 0, bufA, 128, 1);
    k_prop<<<CDIV(Npad * 8, 256), 256, 0, stream>>>(bufA, rowp, degi, csr, dinv, gcn_b, 1, N, Npad, bufB);
    k_stats<<<256, 256, 0, stream>>>(bufB, N, part);
    k_bnfinal<<<1, 128, 0, stream>>>(part, 256, (float)N, bn_g, bn_b, bnst);
    k_apply<<<CDIV(Npad * 64, 256), 256, 0, stream>>>(bufB, bnst, xs, N, Npad);

    // --- SGConv stack: prop -> lin(+bias[,relu]) [-> BN] ---
    for (int i = 0; i < 3; ++i) {
        k_prop<<<CDIV(Npad * 8, 256), 256, 0, stream>>>(xs + (size_t)i * Npad * 128, rowp, degi, csr, dinv,
                                                        nullptr, 0, N, Npad, bufA);
        unsigned short* dst = (i < 2) ? bufB : xs + (size_t)3 * Npad * 128;
        k_gemm<0><<<MT, 256, 32768, stream>>>(bufA, 128, 128, nullptr, 0, 128,
                                              sgT + (size_t)i * 128 * 128, 128,
                                              nullptr, nullptr, 0, sg_b + i * 128, (i < 2) ? 1 : 0, dst, 128, 1);
        if (i < 2) {
            k_stats<<<256, 256, 0, stream>>>(bufB, N, part);
            k_bnfinal<<<1, 128, 0, stream>>>(part, 256, (float)N, bn_g, bn_b, bnst);
            k_apply<<<CDIV(Npad * 64, 256), 256, 0, stream>>>(bufB, bnst, xs + (size_t)(i + 1) * Npad * 128, N, Npad);
        }
    }

    // --- fused bidirectional LSTM + attention scores ---
    k_lstm_fused<<<Npad / 32, 256, 0, stream>>>(xs, BTf, BTb, biasf, biasb, att_w, scores, N, Npad);

    // --- JK pooling ---
    k_jk<<<CDIV(N * 64, 256), 256, 0, stream>>>(scores, xs, jk, N, Npad);

    // --- edge predictor ---
    const int MTe = ELpad / 128;
    k_gemm<1><<<MTe, 256, 32768, stream>>>(jk, 128, 128, nullptr, 0, 256, p1T, 256,
                                           eli, eli + EL, EL, p1_b, 1, z1, 128, 1);
    k_stats<<<256, 256, 0, stream>>>(z1, EL, part);
    k_bnfinal<<<1, 128, 0, stream>>>(part, 256, (float)EL, pbn_g, pbn_b, bnst);
    k_final<<<CDIV(EL * 64, 256), 256, 0, stream>>>(z1, bnst, p2_w, p2_b, (float*)d_out, EL);
    (void)n_in; (void)out_size;
}

// Round 18
// 2428.886 us; speedup vs baseline: 1.4404x; 1.4404x over previous
//
#include <hip/hip_runtime.h>
#include <cstdint>

#define CDIV(a,b) (((a)+(b)-1)/(b))

typedef __bf16 bf16x8 __attribute__((ext_vector_type(8)));
typedef float  f32x4  __attribute__((ext_vector_type(4)));

__device__ __forceinline__ float bf2f(unsigned short u) {
    unsigned v = ((unsigned)u) << 16;
    float f; __builtin_memcpy(&f, &v, 4); return f;
}
__device__ __forceinline__ unsigned short f2bf(float f) {
    unsigned u; __builtin_memcpy(&u, &f, 4);
    u += 0x7fffu + ((u >> 16) & 1u);
    return (unsigned short)(u >> 16);
}
__device__ __forceinline__ float fsig(float x) { return 1.f / (1.f + __expf(-x)); }
__device__ __forceinline__ float ftanh(float x) { return 2.f * fsig(2.f * x) - 1.f; }

__device__ __forceinline__ void gld_lds16(const void* g, void* l) {
    __builtin_amdgcn_global_load_lds((__attribute__((address_space(1))) void*)(g),
                                     (__attribute__((address_space(3))) void*)(l), 16, 0, 0);
}

// ---------------- misc small kernels ----------------

__global__ __launch_bounds__(256) void k_zero4(uint4* p, size_t n4) {
    size_t i = (size_t)blockIdx.x * 256 + threadIdx.x;
    if (i < n4) p[i] = make_uint4(0, 0, 0, 0);
}

__global__ __launch_bounds__(256) void k_deg(const int* ei, int* degi, int E) {
    int e = blockIdx.x * 256 + threadIdx.x;
    if (e < E) atomicAdd(&degi[ei[E + e]], 1);
}

__global__ __launch_bounds__(256) void k_dinv(const int* degi, float* dinv, int N) {
    int n = blockIdx.x * 256 + threadIdx.x;
    if (n < N) dinv[n] = rsqrtf((float)degi[n] + 1.f);
}

#define SCAN_B 2048
__global__ __launch_bounds__(256) void k_scan1(const int* in, int* out, int* bsum, int n) {
    __shared__ int ls[256];
    int b = blockIdx.x, t = threadIdx.x;
    int base = b * SCAN_B + t * 8;
    int v[8]; int s = 0;
#pragma unroll
    for (int i = 0; i < 8; ++i) { int idx = base + i; v[i] = (idx < n) ? in[idx] : 0; s += v[i]; }
    ls[t] = s; __syncthreads();
    for (int off = 1; off < 256; off <<= 1) {
        int x = (t >= off) ? ls[t - off] : 0;
        __syncthreads();
        ls[t] += x;
        __syncthreads();
    }
    int ex = ls[t] - s;
    if (t == 255) bsum[b] = ls[255];
    int run = ex;
#pragma unroll
    for (int i = 0; i < 8; ++i) { int idx = base + i; if (idx < n) out[idx] = run; run += v[i]; }
}
__global__ void k_scan2(int* bsum, int nb) {
    if (threadIdx.x == 0) {
        int acc = 0;
        for (int b = 0; b < nb; ++b) { int v = bsum[b]; bsum[b] = acc; acc += v; }
    }
}
__global__ __launch_bounds__(256) void k_scan3(int* rowp, int* curs, const int* bsum, int n) {
    int i = blockIdx.x * 256 + threadIdx.x;
    if (i < n) { int v = rowp[i] + bsum[i / SCAN_B]; rowp[i] = v; curs[i] = v; }
}
__global__ __launch_bounds__(256) void k_fill(const int* ei, int* curs, int* csr, int E) {
    int e = blockIdx.x * 256 + threadIdx.x;
    if (e < E) { int d = ei[E + e]; int pos = atomicAdd(&curs[d], 1); csr[pos] = ei[e]; }
}

__global__ __launch_bounds__(256) void k_xconv(const float* x, unsigned short* xb, int N, int Npad) {
    int idx = blockIdx.x * 256 + threadIdx.x;
    if (idx >= Npad * 64) return;
    int n = idx >> 6, q = idx & 63;
    ushort2 o;
    if (n < N) {
        float2 v = *(const float2*)&x[(size_t)n * 128 + q * 2];
        o = make_ushort2(f2bf(v.x), f2bf(v.y));
    } else o = make_ushort2(0, 0);
    *(ushort2*)&xb[(size_t)n * 128 + q * 2] = o;
}

__global__ __launch_bounds__(256) void k_packT(const float* W, unsigned short* BT, int K, int Nout) {
    int idx = blockIdx.x * 256 + threadIdx.x;
    if (idx >= K * Nout) return;
    int o = idx / K, k = idx % K;
    BT[idx] = f2bf(W[(size_t)k * Nout + o]);
}

// LSTM weight pack v4: gate-paired, frag-contiguous.
__global__ __launch_bounds__(256) void k_packlstm4(const float* wih, const float* whh, unsigned short* BT) {
    int idx = blockIdx.x * 256 + threadIdx.x;
    if (idx >= 1024 * 384) return;
    int e = idx & 7, u = idx >> 3;
    int l4 = u & 3, l15 = (u >> 2) & 15, ni = (u >> 6) & 1;
    int rest = u >> 7;
    int ks = rest % 12, G = rest / 12;
    int gate = ni * 2 + (l15 >> 3);
    int hid = G * 8 + (l15 & 7);
    int srow = gate * 256 + hid;
    int k = ks * 32 + l4 * 8 + e;
    float v = (k < 128) ? wih[(size_t)srow * 128 + k] : whh[(size_t)srow * 256 + (k - 128)];
    BT[idx] = f2bf(v);
}
__global__ __launch_bounds__(256) void k_packbias4(const float* bih, const float* bhh, float* bias) {
    int c = blockIdx.x * 256 + threadIdx.x;
    if (c >= 1024) return;
    int G = c >> 5, cc = c & 31;
    int ni = cc >> 4, ll = cc & 15;
    int gate = ni * 2 + (ll >> 3);
    int hid = G * 8 + (ll & 7);
    int srow = gate * 256 + hid;
    bias[c] = bih[srow] + bhh[srow];
}

// ---------------- graph propagation (CSR gather, 8 nodes/wave, 2-stage pipeline) ----------------

__global__ __launch_bounds__(256) void k_prop(const unsigned short* __restrict__ X,
                                              const int* __restrict__ rowp, const int* __restrict__ cnt,
                                              const int* __restrict__ csr, const float* __restrict__ dinv,
                                              const float* __restrict__ bias, int relu,
                                              int N, int Npad, unsigned short* __restrict__ OUT) {
    int node = (blockIdx.x * 256 + threadIdx.x) >> 3;
    if (node >= Npad) return;
    const int g = threadIdx.x & 7;
    unsigned short* op = OUT + (size_t)node * 128 + g * 16;
    if (node >= N) {
        *(uint4*)op = make_uint4(0, 0, 0, 0);
        *(uint4*)(op + 8) = make_uint4(0, 0, 0, 0);
        return;
    }
    const int beg = rowp[node], num = cnt[node];
    const float di = dinv[node];
    float a[16];
#pragma unroll
    for (int j = 0; j < 16; ++j) a[j] = 0.f;
    if (num > 0) {
        int s = csr[beg];
        float ws = dinv[s];
        const unsigned short* rp = &X[(size_t)s * 128 + g * 16];
        uint4 qa = *(const uint4*)rp;
        uint4 qb = *(const uint4*)(rp + 8);
        for (int i = 0; i < num; ++i) {
            int sn = (i + 1 < num) ? csr[beg + i + 1] : s;
            float wn = dinv[sn];
            const unsigned short* rn = &X[(size_t)sn * 128 + g * 16];
            uint4 pa = *(const uint4*)rn;
            uint4 pb = *(const uint4*)(rn + 8);
            a[0]  = fmaf(ws, bf2f((unsigned short)(qa.x & 0xffffu)), a[0]);
            a[1]  = fmaf(ws, bf2f((unsigned short)(qa.x >> 16)), a[1]);
            a[2]  = fmaf(ws, bf2f((unsigned short)(qa.y & 0xffffu)), a[2]);
            a[3]  = fmaf(ws, bf2f((unsigned short)(qa.y >> 16)), a[3]);
            a[4]  = fmaf(ws, bf2f((unsigned short)(qa.z & 0xffffu)), a[4]);
            a[5]  = fmaf(ws, bf2f((unsigned short)(qa.z >> 16)), a[5]);
            a[6]  = fmaf(ws, bf2f((unsigned short)(qa.w & 0xffffu)), a[6]);
            a[7]  = fmaf(ws, bf2f((unsigned short)(qa.w >> 16)), a[7]);
            a[8]  = fmaf(ws, bf2f((unsigned short)(qb.x & 0xffffu)), a[8]);
            a[9]  = fmaf(ws, bf2f((unsigned short)(qb.x >> 16)), a[9]);
            a[10] = fmaf(ws, bf2f((unsigned short)(qb.y & 0xffffu)), a[10]);
            a[11] = fmaf(ws, bf2f((unsigned short)(qb.y >> 16)), a[11]);
            a[12] = fmaf(ws, bf2f((unsigned short)(qb.z & 0xffffu)), a[12]);
            a[13] = fmaf(ws, bf2f((unsigned short)(qb.z >> 16)), a[13]);
            a[14] = fmaf(ws, bf2f((unsigned short)(qb.w & 0xffffu)), a[14]);
            a[15] = fmaf(ws, bf2f((unsigned short)(qb.w >> 16)), a[15]);
            s = sn; ws = wn; qa = pa; qb = pb;
        }
    }
    const unsigned short* xp = &X[(size_t)node * 128 + g * 16];
    uint4 xa = *(const uint4*)xp;
    uint4 xb4 = *(const uint4*)(xp + 8);
    const float dd = di * di;
    float o[16];
    o[0]  = di * a[0]  + dd * bf2f((unsigned short)(xa.x & 0xffffu));
    o[1]  = di * a[1]  + dd * bf2f((unsigned short)(xa.x >> 16));
    o[2]  = di * a[2]  + dd * bf2f((unsigned short)(xa.y & 0xffffu));
    o[3]  = di * a[3]  + dd * bf2f((unsigned short)(xa.y >> 16));
    o[4]  = di * a[4]  + dd * bf2f((unsigned short)(xa.z & 0xffffu));
    o[5]  = di * a[5]  + dd * bf2f((unsigned short)(xa.z >> 16));
    o[6]  = di * a[6]  + dd * bf2f((unsigned short)(xa.w & 0xffffu));
    o[7]  = di * a[7]  + dd * bf2f((unsigned short)(xa.w >> 16));
    o[8]  = di * a[8]  + dd * bf2f((unsigned short)(xb4.x & 0xffffu));
    o[9]  = di * a[9]  + dd * bf2f((unsigned short)(xb4.x >> 16));
    o[10] = di * a[10] + dd * bf2f((unsigned short)(xb4.y & 0xffffu));
    o[11] = di * a[11] + dd * bf2f((unsigned short)(xb4.y >> 16));
    o[12] = di * a[12] + dd * bf2f((unsigned short)(xb4.z & 0xffffu));
    o[13] = di * a[13] + dd * bf2f((unsigned short)(xb4.z >> 16));
    o[14] = di * a[14] + dd * bf2f((unsigned short)(xb4.w & 0xffffu));
    o[15] = di * a[15] + dd * bf2f((unsigned short)(xb4.w >> 16));
    if (bias) {
        const float* bp = bias + g * 16;
#pragma unroll
        for (int j = 0; j < 16; ++j) o[j] += bp[j];
    }
    if (relu) {
#pragma unroll
        for (int j = 0; j < 16; ++j) o[j] = fmaxf(o[j], 0.f);
    }
    uint4 r0, r1;
    r0.x = (unsigned)f2bf(o[0])  | ((unsigned)f2bf(o[1])  << 16);
    r0.y = (unsigned)f2bf(o[2])  | ((unsigned)f2bf(o[3])  << 16);
    r0.z = (unsigned)f2bf(o[4])  | ((unsigned)f2bf(o[5])  << 16);
    r0.w = (unsigned)f2bf(o[6])  | ((unsigned)f2bf(o[7])  << 16);
    r1.x = (unsigned)f2bf(o[8])  | ((unsigned)f2bf(o[9])  << 16);
    r1.y = (unsigned)f2bf(o[10]) | ((unsigned)f2bf(o[11]) << 16);
    r1.z = (unsigned)f2bf(o[12]) | ((unsigned)f2bf(o[13]) << 16);
    r1.w = (unsigned)f2bf(o[14]) | ((unsigned)f2bf(o[15]) << 16);
    *(uint4*)op = r0;
    *(uint4*)(op + 8) = r1;
}

// ---------------- batchnorm stats / apply ----------------

__global__ __launch_bounds__(256) void k_stats(const unsigned short* __restrict__ X, int rows, float* part) {
    __shared__ float ls[512];
    int t = threadIdx.x, b = blockIdx.x;
    int ch = t & 127, half = t >> 7;
    float s = 0.f, s2 = 0.f;
    for (int r = b * 2 + half; r < rows; r += 512) {
        float v = bf2f(X[(size_t)r * 128 + ch]);
        s += v; s2 += v * v;
    }
    ls[t] = s; ls[256 + t] = s2;
    __syncthreads();
    if (t < 128) {
        part[b * 256 + t] = ls[t] + ls[t + 128];
        part[b * 256 + 128 + t] = ls[256 + t] + ls[256 + t + 128];
    }
}
__global__ void k_bnfinal(const float* part, int nb, float rows,
                          const float* gamma, const float* beta, float* bnst) {
    int ch = threadIdx.x;
    if (ch >= 128) return;
    float s = 0.f, s2 = 0.f;
    for (int b = 0; b < nb; ++b) { s += part[b * 256 + ch]; s2 += part[b * 256 + 128 + ch]; }
    float mu = s / rows, var = s2 / rows - mu * mu;
    float sc = gamma[ch] * rsqrtf(var + 1e-5f);
    bnst[ch] = sc;
    bnst[128 + ch] = beta[ch] - mu * sc;
}
__global__ __launch_bounds__(256) void k_apply(const unsigned short* in, const float* bnst,
                                               unsigned short* outv, int N, int Npad) {
    int idx = blockIdx.x * 256 + threadIdx.x;
    if (idx >= Npad * 64) return;
    int n = idx >> 6, q = idx & 63;
    ushort2 o;
    if (n < N) {
        ushort2 v = *(const ushort2*)&in[(size_t)n * 128 + q * 2];
        int c0 = q * 2;
        o = make_ushort2(f2bf(bf2f(v.x) * bnst[c0] + bnst[128 + c0]),
                         f2bf(bf2f(v.y) * bnst[c0 + 1] + bnst[128 + c0 + 1]));
    } else o = make_ushort2(0, 0);
    *(ushort2*)&outv[(size_t)n * 128 + q * 2] = o;
}

// ---------------- GEMM core: 128x128 tile, BK=64, 16x16x32 bf16 MFMA ----------------

template<int GATHER>
__device__ __forceinline__ void gemm_core(
    const unsigned short* __restrict__ A0, int lda0, int K0,
    const unsigned short* __restrict__ A1, int lda1, int Ktot,
    const unsigned short* __restrict__ BT, int ldb,
    const int* __restrict__ gR, const int* __restrict__ gC, int ELr,
    int m0, int c0, unsigned short* sA, unsigned short* sB, f32x4 acc[4][4]) {
    const int tid = threadIdx.x;
    const int wid = tid >> 6, lane = tid & 63;
    const int l15 = lane & 15, l4 = lane >> 4;
    const int wr = (wid >> 1) * 64, wc = (wid & 1) * 64;
    const int crow = lane >> 3;
    const int cslot = (lane & 7) ^ crow;
    const int nK = Ktot >> 6;
    for (int ks = 0; ks < nK; ++ks) {
        const int k0 = ks << 6;
#pragma unroll
        for (int i = 0; i < 4; ++i) {
            const int chunk = wid * 4 + i;
            const int row = chunk * 8 + crow;
            const unsigned short* bs = BT + (size_t)(c0 + row) * ldb + k0 + (cslot << 3);
            gld_lds16(bs, sB + chunk * 512);
            if constexpr (GATHER) {
                int e = m0 + row; if (e >= ELr) e = ELr - 1;
                const int nid = (k0 < K0) ? gR[e] : gC[e];
                const unsigned short* as = A0 + (size_t)nid * lda0 + (k0 & (K0 - 1)) + (lane & 7) * 8;
                *(uint4*)(sA + chunk * 512 + crow * 64 + (((lane & 7) ^ crow) << 3)) = *(const uint4*)as;
            } else {
                const unsigned short* as = (k0 < K0)
                    ? A0 + (size_t)(m0 + row) * lda0 + k0 + (cslot << 3)
                    : A1 + (size_t)(m0 + row) * lda1 + (k0 - K0) + (cslot << 3);
                gld_lds16(as, sA + chunk * 512);
            }
        }
        __syncthreads();
#pragma unroll
        for (int kk = 0; kk < 2; ++kk) {
            const int c8 = kk * 4 + l4;
            const int rs = l15 & 7;
            bf16x8 av[4], bv[4];
#pragma unroll
            for (int i = 0; i < 4; ++i)
                av[i] = *(const bf16x8*)(sA + (wr + i * 16 + l15) * 64 + ((c8 ^ rs) << 3));
#pragma unroll
            for (int i = 0; i < 4; ++i)
                bv[i] = *(const bf16x8*)(sB + (wc + i * 16 + l15) * 64 + ((c8 ^ rs) << 3));
#pragma unroll
            for (int mi = 0; mi < 4; ++mi)
#pragma unroll
                for (int ni = 0; ni < 4; ++ni)
                    acc[mi][ni] = __builtin_amdgcn_mfma_f32_16x16x32_bf16(av[mi], bv[ni], acc[mi][ni], 0, 0, 0);
        }
        __syncthreads();
    }
}

template<int GATHER>
__global__ __launch_bounds__(256) void k_gemm(
    const unsigned short* __restrict__ A0, int lda0, int K0,
    const unsigned short* __restrict__ A1, int lda1, int Ktot,
    const unsigned short* __restrict__ BT, int ldb,
    const int* __restrict__ gR, const int* __restrict__ gC, int ELr,
    const float* __restrict__ bias, int relu,
    unsigned short* __restrict__ C, int ldc, int NT) {
    extern __shared__ char smem[];
    unsigned short* sA = (unsigned short*)smem;
    unsigned short* sB = (unsigned short*)(smem + 16384);
    int mt = blockIdx.x / NT, nt = blockIdx.x % NT;
    int m0 = mt * 128, c0 = nt * 128;
    f32x4 acc[4][4];
#pragma unroll
    for (int a = 0; a < 4; ++a)
#pragma unroll
        for (int b = 0; b < 4; ++b) acc[a][b] = (f32x4){0.f, 0.f, 0.f, 0.f};
    gemm_core<GATHER>(A0, lda0, K0, A1, lda1, Ktot, BT, ldb, gR, gC, ELr, m0, c0, sA, sB, acc);
    const int tid = threadIdx.x;
    const int wid = tid >> 6, lane = tid & 63;
    const int l15 = lane & 15, l4 = lane >> 4;
    const int wr = (wid >> 1) * 64, wc = (wid & 1) * 64;
#pragma unroll
    for (int ni = 0; ni < 4; ++ni) {
        int col = c0 + wc + ni * 16 + l15;
        float bv = bias ? bias[col] : 0.f;
#pragma unroll
        for (int mi = 0; mi < 4; ++mi) {
            int rbase = m0 + wr + mi * 16 + l4 * 4;
#pragma unroll
            for (int j = 0; j < 4; ++j) {
                float v = acc[mi][ni][j] + bv;
                if (relu) v = fmaxf(v, 0.f);
                C[(size_t)(rbase + j) * ldc + col] = f2bf(v);
            }
        }
    }
}

// ---------------- fused bidirectional LSTM v12 (r14/r16-verified, byte-identical) ----------------

__global__ __launch_bounds__(512)
void k_lstm_fused(
    const unsigned short* __restrict__ xs,     // [4][Npad][128]
    const unsigned short* __restrict__ BT2f, const unsigned short* __restrict__ BT2b,
    const float* __restrict__ bias2f, const float* __restrict__ bias2b,
    const float* __restrict__ att_w,           // [512]
    float* __restrict__ scores,                // [4][N]
    int N, int Npad) {
    __shared__ char shx[64 * 128 * 2];           // 16KB: xls during GEMM, sc_ld after
    __shared__ unsigned short hbuf[2][64 * 256]; // 2x32KB h dbuf, swizzled
    unsigned short* xls = (unsigned short*)shx;
    float* sc_ld = (float*)shx;                  // [8][64]

    const int tid = threadIdx.x;
    const int wid = tid >> 6, lane = tid & 63;
    const int l15 = lane & 15, l4 = lane >> 4;
    const int rs = l15 & 7;
    const int m0 = blockIdx.x * 64;
    const int loff = (l15 * 4 + l4) * 8;         // frag lane offset (shorts)
    const bool hi = (l15 & 8) != 0;

    float scl[4] = {0.f, 0.f, 0.f, 0.f};         // meaningful for tid<64

#pragma unroll 1
    for (int dir = 0; dir < 2; ++dir) {
        const unsigned short* BT2 = dir ? BT2b : BT2f;
        const float* bias2 = dir ? bias2b : bias2f;
        const float* attw = att_w + dir * 256;
        for (int i = tid; i < 2048; i += 512) ((uint4*)hbuf[0])[i] = make_uint4(0, 0, 0, 0);
        __syncthreads();
        unsigned short* hcur = hbuf[0];
        unsigned short* hnxt = hbuf[1];
        float c0[4][2], c1[4][2], c2[4][2], c3[4][2];
#pragma unroll
        for (int a = 0; a < 4; ++a) {
            c0[a][0] = 0.f; c0[a][1] = 0.f; c1[a][0] = 0.f; c1[a][1] = 0.f;
            c2[a][0] = 0.f; c2[a][1] = 0.f; c3[a][0] = 0.f; c3[a][1] = 0.f;
        }

#pragma unroll 1
        for (int t = 0; t < 4; ++t) {
            const int lyr = dir ? (3 - t) : t;
            // stage xls (pre-swizzled global source -> linear LDS dest)
            {
                const unsigned short* xl = xs + (size_t)lyr * Npad * 128;
#pragma unroll
                for (int i = 0; i < 2; ++i) {
                    int chunk = wid * 2 + i;
                    int row = chunk * 4 + l4;
                    gld_lds16(xl + (size_t)(m0 + row) * 128 + ((l15 ^ (row & 7)) << 3),
                              xls + chunk * 512);
                }
            }
            __syncthreads();   // B1: xls ready; h(t-1) visible

            float scA[4], scB[4];
#pragma unroll
            for (int a = 0; a < 4; ++a) { scA[a] = 0.f; scB[a] = 0.f; }

#define DO_PASS(P, cp)                                                               \
            {                                                                        \
                const int G = wid * 4 + (P);                                         \
                f32x4 acc[4][2];                                                     \
                _Pragma("unroll")                                                    \
                for (int a = 0; a < 4; ++a) {                                        \
                    acc[a][0] = (f32x4){0.f, 0.f, 0.f, 0.f};                         \
                    acc[a][1] = (f32x4){0.f, 0.f, 0.f, 0.f};                         \
                }                                                                    \
                const unsigned short* bpp = BT2 + (size_t)G * 12288 + loff;          \
                _Pragma("unroll 1")                                                  \
                for (int ks = 0; ks < 4; ++ks) {                                     \
                    bf16x8 bv0 = *(const bf16x8*)(bpp + (ks * 2 + 0) * 512);         \
                    bf16x8 bv1 = *(const bf16x8*)(bpp + (ks * 2 + 1) * 512);         \
                    _Pragma("unroll")                                                \
                    for (int mi = 0; mi < 4; ++mi) {                                 \
                        bf16x8 av = *(const bf16x8*)(xls + (mi * 16 + l15) * 128 +   \
                                                     (((ks * 4 + l4) ^ rs) << 3));   \
                        acc[mi][0] = __builtin_amdgcn_mfma_f32_16x16x32_bf16(av, bv0, acc[mi][0], 0, 0, 0); \
                        acc[mi][1] = __builtin_amdgcn_mfma_f32_16x16x32_bf16(av, bv1, acc[mi][1], 0, 0, 0); \
                    }                                                                \
                }                                                                    \
                _Pragma("unroll 1")                                                  \
                for (int ks = 4; ks < 12; ++ks) {                                    \
                    bf16x8 bv0 = *(const bf16x8*)(bpp + (ks * 2 + 0) * 512);         \
                    bf16x8 bv1 = *(const bf16x8*)(bpp + (ks * 2 + 1) * 512);         \
                    _Pragma("unroll")                                                \
                    for (int mi = 0; mi < 4; ++mi) {                                 \
                        bf16x8 av = *(const bf16x8*)(hcur + (mi * 16 + l15) * 256 +  \
                                                     ((((ks - 4) * 4 + l4) ^ rs) << 3)); \
                        acc[mi][0] = __builtin_amdgcn_mfma_f32_16x16x32_bf16(av, bv0, acc[mi][0], 0, 0, 0); \
                        acc[mi][1] = __builtin_amdgcn_mfma_f32_16x16x32_bf16(av, bv1, acc[mi][1], 0, 0, 0); \
                    }                                                                \
                }                                                                    \
                const float bi0 = bias2[G * 32 + l15];                               \
                const float bi1 = bias2[G * 32 + 16 + l15];                          \
                const float aw = attw[G * 8 + (l15 & 7)];                            \
                _Pragma("unroll")                                                    \
                for (int mi = 0; mi < 4; ++mi) {                                     \
                    float a00 = acc[mi][0][0] + bi0, a01 = acc[mi][0][1] + bi0;      \
                    float a02 = acc[mi][0][2] + bi0, a03 = acc[mi][0][3] + bi0;      \
                    float a10 = acc[mi][1][0] + bi1, a11 = acc[mi][1][1] + bi1;      \
                    float a12 = acc[mi][1][2] + bi1, a13 = acc[mi][1][3] + bi1;      \
                    float r0 = __shfl_xor(hi ? a00 : a02, 8);                        \
                    float r1 = __shfl_xor(hi ? a01 : a03, 8);                        \
                    float r2 = __shfl_xor(hi ? a10 : a12, 8);                        \
                    float r3 = __shfl_xor(hi ? a11 : a13, 8);                        \
                    float iA = hi ? r0  : a00,  fA = hi ? a02 : r0;                  \
                    float gA = hi ? r2  : a10,  oA = hi ? a12 : r2;                  \
                    float iB = hi ? r1  : a01,  fB = hi ? a03 : r1;                  \
                    float gB = hi ? r3  : a11,  oB = hi ? a13 : r3;                  \
                    const int rA = mi * 16 + l4 * 4 + (hi ? 2 : 0);                  \
                    {                                                                \
                        float gi = fsig(iA), gf = fsig(fA), gg = ftanh(gA), go = fsig(oA); \
                        float cc = fmaf(gf, cp[mi][0], gi * gg);                     \
                        cp[mi][0] = cc;                                              \
                        float hn = go * ftanh(cc);                                   \
                        scA[mi] = fmaf(hn, aw, scA[mi]);                             \
                        *(unsigned short*)((char*)hnxt + rA * 512 +                  \
                                           ((G ^ (rA & 7)) << 4) + (l15 & 7) * 2) = f2bf(hn); \
                    }                                                                \
                    {                                                                \
                        const int rB = rA + 1;                                       \
                        float gi = fsig(iB), gf = fsig(fB), gg = ftanh(gB), go = fsig(oB); \
                        float cc = fmaf(gf, cp[mi][1], gi * gg);                     \
                        cp[mi][1] = cc;                                              \
                        float hn = go * ftanh(cc);                                   \
                        scB[mi] = fmaf(hn, aw, scB[mi]);                             \
                        *(unsigned short*)((char*)hnxt + rB * 512 +                  \
                                           ((G ^ (rB & 7)) << 4) + (l15 & 7) * 2) = f2bf(hn); \
                    }                                                                \
                }                                                                    \
            }

            DO_PASS(0, c0)
            DO_PASS(1, c1)
            DO_PASS(2, c2)
            DO_PASS(3, c3)
#undef DO_PASS

            __syncthreads();   // B2: all xls/h(t-1) reads + hnxt writes done
            // publish per-row score partials into sc_ld (aliases xls - safe now)
#pragma unroll
            for (int mi = 0; mi < 4; ++mi) {
                float sA = scA[mi], sB = scB[mi];
                sA += __shfl_xor(sA, 1); sA += __shfl_xor(sA, 2); sA += __shfl_xor(sA, 4);
                sB += __shfl_xor(sB, 1); sB += __shfl_xor(sB, 2); sB += __shfl_xor(sB, 4);
                if ((l15 & 7) == 0) {
                    int row = mi * 16 + l4 * 4 + (hi ? 2 : 0);
                    sc_ld[wid * 64 + row] = sA;
                    sc_ld[wid * 64 + row + 1] = sB;
                }
            }
            __syncthreads();   // B3: sc visible
            if (tid < 64) {
                float s = 0.f;
#pragma unroll
                for (int w = 0; w < 8; ++w) s += sc_ld[w * 64 + tid];
#pragma unroll
                for (int l = 0; l < 4; ++l) scl[l] += (l == lyr) ? s : 0.f;
            }
            __syncthreads();   // B4: consumption done -> shx free for next staging
            unsigned short* tmp = hcur; hcur = hnxt; hnxt = tmp;
        }
    }
    if (tid < 64) {
        int n = m0 + tid;
        if (n < N) {
#pragma unroll
            for (int l = 0; l < 4; ++l) scores[(size_t)l * N + n] = scl[l];
        }
    }
}

// ---------------- JK pooling + final predictor ----------------

__global__ __launch_bounds__(256) void k_jk(const float* __restrict__ sc, const unsigned short* __restrict__ xs,
                                            unsigned short* __restrict__ jk, int N, int Npad) {
    int gw = (blockIdx.x * 256 + threadIdx.x) >> 6;
    if (gw >= N) return;
    int lane = threadIdx.x & 63;
    float s0 = sc[gw], s1 = sc[N + gw], s2 = sc[2 * N + gw], s3 = sc[3 * N + gw];
    float m = fmaxf(fmaxf(s0, s1), fmaxf(s2, s3));
    float e0 = __expf(s0 - m), e1 = __expf(s1 - m), e2 = __expf(s2 - m), e3 = __expf(s3 - m);
    float inv = 1.f / (e0 + e1 + e2 + e3);
    float a0 = e0 * inv, a1 = e1 * inv, a2 = e2 * inv, a3 = e3 * inv;
    size_t stride = (size_t)Npad * 128;
    const unsigned short* p = xs + (size_t)gw * 128 + lane * 2;
    ushort2 v0 = *(const ushort2*)p;
    ushort2 v1 = *(const ushort2*)(p + stride);
    ushort2 v2 = *(const ushort2*)(p + 2 * stride);
    ushort2 v3 = *(const ushort2*)(p + 3 * stride);
    float r0 = a0 * bf2f(v0.x) + a1 * bf2f(v1.x) + a2 * bf2f(v2.x) + a3 * bf2f(v3.x);
    float r1 = a0 * bf2f(v0.y) + a1 * bf2f(v1.y) + a2 * bf2f(v2.y) + a3 * bf2f(v3.y);
    *(ushort2*)&jk[(size_t)gw * 128 + lane * 2] = make_ushort2(f2bf(r0), f2bf(r1));
}

__global__ __launch_bounds__(256) void k_final(const unsigned short* __restrict__ z1, const float* __restrict__ bnst,
                                               const float* __restrict__ w2, const float* __restrict__ b2,
                                               float* __restrict__ out, int EL) {
    int e = (blockIdx.x * 256 + threadIdx.x) >> 6;
    if (e >= EL) return;
    int lane = threadIdx.x & 63;
    ushort2 z = *(const ushort2*)&z1[(size_t)e * 128 + lane * 2];
    int c0 = lane * 2;
    float y0 = bf2f(z.x) * bnst[c0] + bnst[128 + c0];
    float y1 = bf2f(z.y) * bnst[c0 + 1] + bnst[128 + c0 + 1];
    float p = y0 * w2[c0] + y1 * w2[c0 + 1];
#pragma unroll
    for (int off = 32; off; off >>= 1) p += __shfl_xor(p, off);
    if (lane == 0) out[e] = 1.f / (1.f + __expf(-(p + b2[0])));
}

// ---------------- host ----------------

extern "C" void kernel_launch(void* const* d_in, const int* in_sizes, int n_in,
                              void* d_out, int out_size, void* d_ws, size_t ws_size,
                              hipStream_t stream) {
    const int* ei      = (const int*)d_in[0];
    const float* x     = (const float*)d_in[1];
    const int* eli     = (const int*)d_in[2];
    const float* gcn_w = (const float*)d_in[3];
    const float* gcn_b = (const float*)d_in[4];
    const float* sg_w  = (const float*)d_in[5];
    const float* sg_b  = (const float*)d_in[6];
    const float* bn_g  = (const float*)d_in[7];
    const float* bn_b  = (const float*)d_in[8];
    const float* w_ih_f = (const float*)d_in[9];
    const float* w_hh_f = (const float*)d_in[10];
    const float* b_ih_f = (const float*)d_in[11];
    const float* b_hh_f = (const float*)d_in[12];
    const float* w_ih_b = (const float*)d_in[13];
    const float* w_hh_b = (const float*)d_in[14];
    const float* b_ih_b = (const float*)d_in[15];
    const float* b_hh_b = (const float*)d_in[16];
    const float* att_w = (const float*)d_in[17];
    // d_in[18] = att_b: softmax over layers is shift-invariant -> unused
    const float* p1_w  = (const float*)d_in[19];
    const float* p1_b  = (const float*)d_in[20];
    const float* pbn_g = (const float*)d_in[21];
    const float* pbn_b = (const float*)d_in[22];
    const float* p2_w  = (const float*)d_in[23];
    const float* p2_b  = (const float*)d_in[24];

    const int E = in_sizes[0] / 2;
    const int N = in_sizes[1] / 128;
    const int EL = in_sizes[2] / 2;
    const int Npad = CDIV(N, 128) * 128;
    const int ELpad = CDIV(EL, 128) * 128;
    const size_t NB128 = (size_t)Npad * 128 * 2;

    char* wsp = (char*)d_ws;
    size_t off = 0;
    auto A = [&](size_t b) -> char* {
        char* p = wsp + off;
        off = (off + b + 255) & ~(size_t)255;
        return p;
    };
    // ---- persistent ----
    int* degi = (int*)A((size_t)N * 4);
    float* dinv = (float*)A((size_t)N * 4);
    int* rowp = (int*)A((size_t)N * 4);
    int* curs = (int*)A((size_t)N * 4);
    int* bsum = (int*)A(256 * 4);
    unsigned short* gT   = (unsigned short*)A(128 * 128 * 2);
    unsigned short* sgT  = (unsigned short*)A(3 * 128 * 128 * 2);
    unsigned short* p1T  = (unsigned short*)A(128 * 256 * 2);
    unsigned short* BTf  = (unsigned short*)A(1024 * 384 * 2);
    unsigned short* BTb  = (unsigned short*)A(1024 * 384 * 2);
    float* biasf = (float*)A(1024 * 4);
    float* biasb = (float*)A(1024 * 4);
    float* part = (float*)A(256 * 256 * 4);
    float* bnst = (float*)A(256 * 4);
    float* scores = (float*)A((size_t)4 * N * 4);
    unsigned short* xs = (unsigned short*)A(NB128 * 4);
    // ---- phase-aliased arena ----
    const size_t arena0 = off;
    int* csr = (int*)A((size_t)E * 4);
    unsigned short* xb   = (unsigned short*)A(NB128);
    unsigned short* bufA = (unsigned short*)A(NB128);
    unsigned short* bufB = (unsigned short*)A(NB128);
    const size_t convEnd = off;
    off = arena0;
    unsigned short* jk = (unsigned short*)A((size_t)N * 128 * 2);
    unsigned short* z1 = (unsigned short*)A((size_t)ELpad * 128 * 2);
    const size_t predEnd = off;
    if (convEnd > ws_size || predEnd > ws_size) return;  // workspace too small

    // --- degree, dinv, CSR ---
    k_zero4<<<CDIV((size_t)N * 4, 16 * 256), 256, 0, stream>>>((uint4*)degi, CDIV((size_t)N * 4, 16));
    k_deg<<<CDIV(E, 256), 256, 0, stream>>>(ei, degi, E);
    k_dinv<<<CDIV(N, 256), 256, 0, stream>>>(degi, dinv, N);
    int nb = CDIV(N, SCAN_B);
    k_scan1<<<nb, 256, 0, stream>>>(degi, rowp, bsum, N);
    k_scan2<<<1, 64, 0, stream>>>(bsum, nb);
    k_scan3<<<CDIV(N, 256), 256, 0, stream>>>(rowp, curs, bsum, N);
    k_fill<<<CDIV(E, 256), 256, 0, stream>>>(ei, curs, csr, E);

    // --- convert + weight packs ---
    k_xconv<<<CDIV(Npad * 64, 256), 256, 0, stream>>>(x, xb, N, Npad);
    k_packT<<<CDIV(128 * 128, 256), 256, 0, stream>>>(gcn_w, gT, 128, 128);
    for (int i = 0; i < 3; ++i)
        k_packT<<<CDIV(128 * 128, 256), 256, 0, stream>>>(sg_w + (size_t)i * 128 * 128, sgT + (size_t)i * 128 * 128, 128, 128);
    k_packT<<<CDIV(256 * 128, 256), 256, 0, stream>>>(p1_w, p1T, 256, 128);
    k_packlstm4<<<CDIV(1024 * 384, 256), 256, 0, stream>>>(w_ih_f, w_hh_f, BTf);
    k_packlstm4<<<CDIV(1024 * 384, 256), 256, 0, stream>>>(w_ih_b, w_hh_b, BTb);
    k_packbias4<<<4, 256, 0, stream>>>(b_ih_f, b_hh_f, biasf);
    k_packbias4<<<4, 256, 0, stream>>>(b_ih_b, b_hh_b, biasb);

    const int MT = Npad / 128;
    // --- GCNConv: lin -> prop(+bias,relu) -> BN ---
    k_gemm<0><<<MT, 256, 32768, stream>>>(xb, 128, 128, nullptr, 0, 128, gT, 128,
                                          nullptr, nullptr, 0, nullptr, 0, bufA, 128, 1);
    k_prop<<<CDIV(Npad * 8, 256), 256, 0, stream>>>(bufA, rowp, degi, csr, dinv, gcn_b, 1, N, Npad, bufB);
    k_stats<<<256, 256, 0, stream>>>(bufB, N, part);
    k_bnfinal<<<1, 128, 0, stream>>>(part, 256, (float)N, bn_g, bn_b, bnst);
    k_apply<<<CDIV(Npad * 64, 256), 256, 0, stream>>>(bufB, bnst, xs, N, Npad);

    // --- SGConv stack: prop -> lin(+bias[,relu]) [-> BN] ---
    for (int i = 0; i < 3; ++i) {
        k_prop<<<CDIV(Npad * 8, 256), 256, 0, stream>>>(xs + (size_t)i * Npad * 128, rowp, degi, csr, dinv,
                                                        nullptr, 0, N, Npad, bufA);
        unsigned short* dst = (i < 2) ? bufB : xs + (size_t)3 * Npad * 128;
        k_gemm<0><<<MT, 256, 32768, stream>>>(bufA, 128, 128, nullptr, 0, 128,
                                              sgT + (size_t)i * 128 * 128, 128,
                                              nullptr, nullptr, 0, sg_b + i * 128, (i < 2) ? 1 : 0, dst, 128, 1);
        if (i < 2) {
            k_stats<<<256, 256, 0, stream>>>(bufB, N, part);
            k_bnfinal<<<1, 128, 0, stream>>>(part, 256, (float)N, bn_g, bn_b, bnst);
            k_apply<<<CDIV(Npad * 64, 256), 256, 0, stream>>>(bufB, bnst, xs + (size_t)(i + 1) * Npad * 128, N, Npad);
        }
    }

    // --- fused bidirectional LSTM + attention scores ---
    k_lstm_fused<<<Npad / 64, 512, 0, stream>>>(xs, BTf, BTb, biasf, biasb, att_w, scores, N, Npad);

    // --- JK pooling ---
    k_jk<<<CDIV(N * 64, 256), 256, 0, stream>>>(scores, xs, jk, N, Npad);

    // --- edge predictor ---
    const int MTe = ELpad / 128;
    k_gemm<1><<<MTe, 256, 32768, stream>>>(jk, 128, 128, nullptr, 0, 256, p1T, 256,
                                           eli, eli + EL, EL, p1_b, 1, z1, 128, 1);
    k_stats<<<256, 256, 0, stream>>>(z1, EL, part);
    k_bnfinal<<<1, 128, 0, stream>>>(part, 256, (float)EL, pbn_g, pbn_b, bnst);
    k_final<<<CDIV(EL * 64, 256), 256, 0, stream>>>(z1, bnst, p2_w, p2_b, (float*)d_out, EL);
    (void)n_in; (void)out_size;
}

// Round 19
// 2334.499 us; speedup vs baseline: 1.4987x; 1.0404x over previous
//
#include <hip/hip_runtime.h>
#include <cstdint>

#define CDIV(a,b) (((a)+(b)-1)/(b))

typedef __bf16 bf16x8 __attribute__((ext_vector_type(8)));
typedef float  f32x4  __attribute__((ext_vector_type(4)));

__device__ __forceinline__ float bf2f(unsigned short u) {
    unsigned v = ((unsigned)u) << 16;
    float f; __builtin_memcpy(&f, &v, 4); return f;
}
__device__ __forceinline__ unsigned short f2bf(float f) {
    unsigned u; __builtin_memcpy(&u, &f, 4);
    u += 0x7fffu + ((u >> 16) & 1u);
    return (unsigned short)(u >> 16);
}
__device__ __forceinline__ float fsig(float x) { return 1.f / (1.f + __expf(-x)); }
__device__ __forceinline__ float ftanh(float x) { return 2.f * fsig(2.f * x) - 1.f; }

__device__ __forceinline__ void gld_lds16(const void* g, void* l) {
    __builtin_amdgcn_global_load_lds((__attribute__((address_space(1))) void*)(g),
                                     (__attribute__((address_space(3))) void*)(l), 16, 0, 0);
}

// ---------------- misc small kernels ----------------

__global__ __launch_bounds__(256) void k_zero4(uint4* p, size_t n4) {
    size_t i = (size_t)blockIdx.x * 256 + threadIdx.x;
    if (i < n4) p[i] = make_uint4(0, 0, 0, 0);
}

__global__ __launch_bounds__(256) void k_deg(const int* ei, int* degi, int E) {
    int e = blockIdx.x * 256 + threadIdx.x;
    if (e < E) atomicAdd(&degi[ei[E + e]], 1);
}

__global__ __launch_bounds__(256) void k_dinv(const int* degi, float* dinv, int N) {
    int n = blockIdx.x * 256 + threadIdx.x;
    if (n < N) dinv[n] = rsqrtf((float)degi[n] + 1.f);
}

#define SCAN_B 2048
__global__ __launch_bounds__(256) void k_scan1(const int* in, int* out, int* bsum, int n) {
    __shared__ int ls[256];
    int b = blockIdx.x, t = threadIdx.x;
    int base = b * SCAN_B + t * 8;
    int v[8]; int s = 0;
#pragma unroll
    for (int i = 0; i < 8; ++i) { int idx = base + i; v[i] = (idx < n) ? in[idx] : 0; s += v[i]; }
    ls[t] = s; __syncthreads();
    for (int off = 1; off < 256; off <<= 1) {
        int x = (t >= off) ? ls[t - off] : 0;
        __syncthreads();
        ls[t] += x;
        __syncthreads();
    }
    int ex = ls[t] - s;
    if (t == 255) bsum[b] = ls[255];
    int run = ex;
#pragma unroll
    for (int i = 0; i < 8; ++i) { int idx = base + i; if (idx < n) out[idx] = run; run += v[i]; }
}
__global__ void k_scan2(int* bsum, int nb) {
    if (threadIdx.x == 0) {
        int acc = 0;
        for (int b = 0; b < nb; ++b) { int v = bsum[b]; bsum[b] = acc; acc += v; }
    }
}
__global__ __launch_bounds__(256) void k_scan3(int* rowp, int* curs, const int* bsum, int n) {
    int i = blockIdx.x * 256 + threadIdx.x;
    if (i < n) { int v = rowp[i] + bsum[i / SCAN_B]; rowp[i] = v; curs[i] = v; }
}
__global__ __launch_bounds__(256) void k_fill(const int* ei, int* curs, int* csr, int E) {
    int e = blockIdx.x * 256 + threadIdx.x;
    if (e < E) { int d = ei[E + e]; int pos = atomicAdd(&curs[d], 1); csr[pos] = ei[e]; }
}

__global__ __launch_bounds__(256) void k_xconv(const float* x, unsigned short* xb, int N, int Npad) {
    int idx = blockIdx.x * 256 + threadIdx.x;
    if (idx >= Npad * 64) return;
    int n = idx >> 6, q = idx & 63;
    ushort2 o;
    if (n < N) {
        float2 v = *(const float2*)&x[(size_t)n * 128 + q * 2];
        o = make_ushort2(f2bf(v.x), f2bf(v.y));
    } else o = make_ushort2(0, 0);
    *(ushort2*)&xb[(size_t)n * 128 + q * 2] = o;
}

__global__ __launch_bounds__(256) void k_packT(const float* W, unsigned short* BT, int K, int Nout) {
    int idx = blockIdx.x * 256 + threadIdx.x;
    if (idx >= K * Nout) return;
    int o = idx / K, k = idx % K;
    BT[idx] = f2bf(W[(size_t)k * Nout + o]);
}

// LSTM weight pack v4: gate-paired, frag-contiguous.
__global__ __launch_bounds__(256) void k_packlstm4(const float* wih, const float* whh, unsigned short* BT) {
    int idx = blockIdx.x * 256 + threadIdx.x;
    if (idx >= 1024 * 384) return;
    int e = idx & 7, u = idx >> 3;
    int l4 = u & 3, l15 = (u >> 2) & 15, ni = (u >> 6) & 1;
    int rest = u >> 7;
    int ks = rest % 12, G = rest / 12;
    int gate = ni * 2 + (l15 >> 3);
    int hid = G * 8 + (l15 & 7);
    int srow = gate * 256 + hid;
    int k = ks * 32 + l4 * 8 + e;
    float v = (k < 128) ? wih[(size_t)srow * 128 + k] : whh[(size_t)srow * 256 + (k - 128)];
    BT[idx] = f2bf(v);
}
__global__ __launch_bounds__(256) void k_packbias4(const float* bih, const float* bhh, float* bias) {
    int c = blockIdx.x * 256 + threadIdx.x;
    if (c >= 1024) return;
    int G = c >> 5, cc = c & 31;
    int ni = cc >> 4, ll = cc & 15;
    int gate = ni * 2 + (ll >> 3);
    int hid = G * 8 + (ll & 7);
    int srow = gate * 256 + hid;
    bias[c] = bih[srow] + bhh[srow];
}

// ---------------- graph propagation (CSR gather, 8 nodes/wave, 2-stage pipeline) ----------------

__global__ __launch_bounds__(256) void k_prop(const unsigned short* __restrict__ X,
                                              const int* __restrict__ rowp, const int* __restrict__ cnt,
                                              const int* __restrict__ csr, const float* __restrict__ dinv,
                                              const float* __restrict__ bias, int relu,
                                              int N, int Npad, unsigned short* __restrict__ OUT) {
    int node = (blockIdx.x * 256 + threadIdx.x) >> 3;
    if (node >= Npad) return;
    const int g = threadIdx.x & 7;
    unsigned short* op = OUT + (size_t)node * 128 + g * 16;
    if (node >= N) {
        *(uint4*)op = make_uint4(0, 0, 0, 0);
        *(uint4*)(op + 8) = make_uint4(0, 0, 0, 0);
        return;
    }
    const int beg = rowp[node], num = cnt[node];
    const float di = dinv[node];
    float a[16];
#pragma unroll
    for (int j = 0; j < 16; ++j) a[j] = 0.f;
    if (num > 0) {
        int s = csr[beg];
        float ws = dinv[s];
        const unsigned short* rp = &X[(size_t)s * 128 + g * 16];
        uint4 qa = *(const uint4*)rp;
        uint4 qb = *(const uint4*)(rp + 8);
        for (int i = 0; i < num; ++i) {
            int sn = (i + 1 < num) ? csr[beg + i + 1] : s;
            float wn = dinv[sn];
            const unsigned short* rn = &X[(size_t)sn * 128 + g * 16];
            uint4 pa = *(const uint4*)rn;
            uint4 pb = *(const uint4*)(rn + 8);
            a[0]  = fmaf(ws, bf2f((unsigned short)(qa.x & 0xffffu)), a[0]);
            a[1]  = fmaf(ws, bf2f((unsigned short)(qa.x >> 16)), a[1]);
            a[2]  = fmaf(ws, bf2f((unsigned short)(qa.y & 0xffffu)), a[2]);
            a[3]  = fmaf(ws, bf2f((unsigned short)(qa.y >> 16)), a[3]);
            a[4]  = fmaf(ws, bf2f((unsigned short)(qa.z & 0xffffu)), a[4]);
            a[5]  = fmaf(ws, bf2f((unsigned short)(qa.z >> 16)), a[5]);
            a[6]  = fmaf(ws, bf2f((unsigned short)(qa.w & 0xffffu)), a[6]);
            a[7]  = fmaf(ws, bf2f((unsigned short)(qa.w >> 16)), a[7]);
            a[8]  = fmaf(ws, bf2f((unsigned short)(qb.x & 0xffffu)), a[8]);
            a[9]  = fmaf(ws, bf2f((unsigned short)(qb.x >> 16)), a[9]);
            a[10] = fmaf(ws, bf2f((unsigned short)(qb.y & 0xffffu)), a[10]);
            a[11] = fmaf(ws, bf2f((unsigned short)(qb.y >> 16)), a[11]);
            a[12] = fmaf(ws, bf2f((unsigned short)(qb.z & 0xffffu)), a[12]);
            a[13] = fmaf(ws, bf2f((unsigned short)(qb.z >> 16)), a[13]);
            a[14] = fmaf(ws, bf2f((unsigned short)(qb.w & 0xffffu)), a[14]);
            a[15] = fmaf(ws, bf2f((unsigned short)(qb.w >> 16)), a[15]);
            s = sn; ws = wn; qa = pa; qb = pb;
        }
    }
    const unsigned short* xp = &X[(size_t)node * 128 + g * 16];
    uint4 xa = *(const uint4*)xp;
    uint4 xb4 = *(const uint4*)(xp + 8);
    const float dd = di * di;
    float o[16];
    o[0]  = di * a[0]  + dd * bf2f((unsigned short)(xa.x & 0xffffu));
    o[1]  = di * a[1]  + dd * bf2f((unsigned short)(xa.x >> 16));
    o[2]  = di * a[2]  + dd * bf2f((unsigned short)(xa.y & 0xffffu));
    o[3]  = di * a[3]  + dd * bf2f((unsigned short)(xa.y >> 16));
    o[4]  = di * a[4]  + dd * bf2f((unsigned short)(xa.z & 0xffffu));
    o[5]  = di * a[5]  + dd * bf2f((unsigned short)(xa.z >> 16));
    o[6]  = di * a[6]  + dd * bf2f((unsigned short)(xa.w & 0xffffu));
    o[7]  = di * a[7]  + dd * bf2f((unsigned short)(xa.w >> 16));
    o[8]  = di * a[8]  + dd * bf2f((unsigned short)(xb4.x & 0xffffu));
    o[9]  = di * a[9]  + dd * bf2f((unsigned short)(xb4.x >> 16));
    o[10] = di * a[10] + dd * bf2f((unsigned short)(xb4.y & 0xffffu));
    o[11] = di * a[11] + dd * bf2f((unsigned short)(xb4.y >> 16));
    o[12] = di * a[12] + dd * bf2f((unsigned short)(xb4.z & 0xffffu));
    o[13] = di * a[13] + dd * bf2f((unsigned short)(xb4.z >> 16));
    o[14] = di * a[14] + dd * bf2f((unsigned short)(xb4.w & 0xffffu));
    o[15] = di * a[15] + dd * bf2f((unsigned short)(xb4.w >> 16));
    if (bias) {
        const float* bp = bias + g * 16;
#pragma unroll
        for (int j = 0; j < 16; ++j) o[j] += bp[j];
    }
    if (relu) {
#pragma unroll
        for (int j = 0; j < 16; ++j) o[j] = fmaxf(o[j], 0.f);
    }
    uint4 r0, r1;
    r0.x = (unsigned)f2bf(o[0])  | ((unsigned)f2bf(o[1])  << 16);
    r0.y = (unsigned)f2bf(o[2])  | ((unsigned)f2bf(o[3])  << 16);
    r0.z = (unsigned)f2bf(o[4])  | ((unsigned)f2bf(o[5])  << 16);
    r0.w = (unsigned)f2bf(o[6])  | ((unsigned)f2bf(o[7])  << 16);
    r1.x = (unsigned)f2bf(o[8])  | ((unsigned)f2bf(o[9])  << 16);
    r1.y = (unsigned)f2bf(o[10]) | ((unsigned)f2bf(o[11]) << 16);
    r1.z = (unsigned)f2bf(o[12]) | ((unsigned)f2bf(o[13]) << 16);
    r1.w = (unsigned)f2bf(o[14]) | ((unsigned)f2bf(o[15]) << 16);
    *(uint4*)op = r0;
    *(uint4*)(op + 8) = r1;
}

// ---------------- batchnorm stats / apply ----------------

__global__ __launch_bounds__(256) void k_stats(const unsigned short* __restrict__ X, int rows, float* part) {
    __shared__ float ls[512];
    int t = threadIdx.x, b = blockIdx.x;
    int ch = t & 127, half = t >> 7;
    float s = 0.f, s2 = 0.f;
    for (int r = b * 2 + half; r < rows; r += 512) {
        float v = bf2f(X[(size_t)r * 128 + ch]);
        s += v; s2 += v * v;
    }
    ls[t] = s; ls[256 + t] = s2;
    __syncthreads();
    if (t < 128) {
        part[b * 256 + t] = ls[t] + ls[t + 128];
        part[b * 256 + 128 + t] = ls[256 + t] + ls[256 + t + 128];
    }
}
__global__ void k_bnfinal(const float* part, int nb, float rows,
                          const float* gamma, const float* beta, float* bnst) {
    int ch = threadIdx.x;
    if (ch >= 128) return;
    float s = 0.f, s2 = 0.f;
    for (int b = 0; b < nb; ++b) { s += part[b * 256 + ch]; s2 += part[b * 256 + 128 + ch]; }
    float mu = s / rows, var = s2 / rows - mu * mu;
    float sc = gamma[ch] * rsqrtf(var + 1e-5f);
    bnst[ch] = sc;
    bnst[128 + ch] = beta[ch] - mu * sc;
}
__global__ __launch_bounds__(256) void k_apply(const unsigned short* in, const float* bnst,
                                               unsigned short* outv, int N, int Npad) {
    int idx = blockIdx.x * 256 + threadIdx.x;
    if (idx >= Npad * 64) return;
    int n = idx >> 6, q = idx & 63;
    ushort2 o;
    if (n < N) {
        ushort2 v = *(const ushort2*)&in[(size_t)n * 128 + q * 2];
        int c0 = q * 2;
        o = make_ushort2(f2bf(bf2f(v.x) * bnst[c0] + bnst[128 + c0]),
                         f2bf(bf2f(v.y) * bnst[c0 + 1] + bnst[128 + c0 + 1]));
    } else o = make_ushort2(0, 0);
    *(ushort2*)&outv[(size_t)n * 128 + q * 2] = o;
}

// ---------------- GEMM core: 128x128 tile, BK=64, 16x16x32 bf16 MFMA ----------------

template<int GATHER>
__device__ __forceinline__ void gemm_core(
    const unsigned short* __restrict__ A0, int lda0, int K0,
    const unsigned short* __restrict__ A1, int lda1, int Ktot,
    const unsigned short* __restrict__ BT, int ldb,
    const int* __restrict__ gR, const int* __restrict__ gC, int ELr,
    int m0, int c0, unsigned short* sA, unsigned short* sB, f32x4 acc[4][4]) {
    const int tid = threadIdx.x;
    const int wid = tid >> 6, lane = tid & 63;
    const int l15 = lane & 15, l4 = lane >> 4;
    const int wr = (wid >> 1) * 64, wc = (wid & 1) * 64;
    const int crow = lane >> 3;
    const int cslot = (lane & 7) ^ crow;
    const int nK = Ktot >> 6;
    for (int ks = 0; ks < nK; ++ks) {
        const int k0 = ks << 6;
#pragma unroll
        for (int i = 0; i < 4; ++i) {
            const int chunk = wid * 4 + i;
            const int row = chunk * 8 + crow;
            const unsigned short* bs = BT + (size_t)(c0 + row) * ldb + k0 + (cslot << 3);
            gld_lds16(bs, sB + chunk * 512);
            if constexpr (GATHER) {
                int e = m0 + row; if (e >= ELr) e = ELr - 1;
                const int nid = (k0 < K0) ? gR[e] : gC[e];
                const unsigned short* as = A0 + (size_t)nid * lda0 + (k0 & (K0 - 1)) + (lane & 7) * 8;
                *(uint4*)(sA + chunk * 512 + crow * 64 + (((lane & 7) ^ crow) << 3)) = *(const uint4*)as;
            } else {
                const unsigned short* as = (k0 < K0)
                    ? A0 + (size_t)(m0 + row) * lda0 + k0 + (cslot << 3)
                    : A1 + (size_t)(m0 + row) * lda1 + (k0 - K0) + (cslot << 3);
                gld_lds16(as, sA + chunk * 512);
            }
        }
        __syncthreads();
#pragma unroll
        for (int kk = 0; kk < 2; ++kk) {
            const int c8 = kk * 4 + l4;
            const int rs = l15 & 7;
            bf16x8 av[4], bv[4];
#pragma unroll
            for (int i = 0; i < 4; ++i)
                av[i] = *(const bf16x8*)(sA + (wr + i * 16 + l15) * 64 + ((c8 ^ rs) << 3));
#pragma unroll
            for (int i = 0; i < 4; ++i)
                bv[i] = *(const bf16x8*)(sB + (wc + i * 16 + l15) * 64 + ((c8 ^ rs) << 3));
#pragma unroll
            for (int mi = 0; mi < 4; ++mi)
#pragma unroll
                for (int ni = 0; ni < 4; ++ni)
                    acc[mi][ni] = __builtin_amdgcn_mfma_f32_16x16x32_bf16(av[mi], bv[ni], acc[mi][ni], 0, 0, 0);
        }
        __syncthreads();
    }
}

template<int GATHER>
__global__ __launch_bounds__(256) void k_gemm(
    const unsigned short* __restrict__ A0, int lda0, int K0,
    const unsigned short* __restrict__ A1, int lda1, int Ktot,
    const unsigned short* __restrict__ BT, int ldb,
    const int* __restrict__ gR, const int* __restrict__ gC, int ELr,
    const float* __restrict__ bias, int relu,
    unsigned short* __restrict__ C, int ldc, int NT) {
    extern __shared__ char smem[];
    unsigned short* sA = (unsigned short*)smem;
    unsigned short* sB = (unsigned short*)(smem + 16384);
    int mt = blockIdx.x / NT, nt = blockIdx.x % NT;
    int m0 = mt * 128, c0 = nt * 128;
    f32x4 acc[4][4];
#pragma unroll
    for (int a = 0; a < 4; ++a)
#pragma unroll
        for (int b = 0; b < 4; ++b) acc[a][b] = (f32x4){0.f, 0.f, 0.f, 0.f};
    gemm_core<GATHER>(A0, lda0, K0, A1, lda1, Ktot, BT, ldb, gR, gC, ELr, m0, c0, sA, sB, acc);
    const int tid = threadIdx.x;
    const int wid = tid >> 6, lane = tid & 63;
    const int l15 = lane & 15, l4 = lane >> 4;
    const int wr = (wid >> 1) * 64, wc = (wid & 1) * 64;
#pragma unroll
    for (int ni = 0; ni < 4; ++ni) {
        int col = c0 + wc + ni * 16 + l15;
        float bv = bias ? bias[col] : 0.f;
#pragma unroll
        for (int mi = 0; mi < 4; ++mi) {
            int rbase = m0 + wr + mi * 16 + l4 * 4;
#pragma unroll
            for (int j = 0; j < 4; ++j) {
                float v = acc[mi][ni][j] + bv;
                if (relu) v = fmaxf(v, 0.f);
                C[(size_t)(rbase + j) * ldc + col] = f2bf(v);
            }
        }
    }
}

// ---------------- fused bidirectional LSTM v13 ----------------
// = r16-verified v12 body with the dir loop hoisted to blockIdx.y (directions are
// independent): halves per-block duration, doubles block count (3128 = 12x256+56)
// -> makespan 6.5 t_blk vs 7 t_blk (load-balance tail). Scores go to per-dir
// buffers summed in k_jk (same fp32 add order -> bit-identical).

__global__ __launch_bounds__(512)
void k_lstm_fused(
    const unsigned short* __restrict__ xs,     // [4][Npad][128]
    const unsigned short* __restrict__ BT2f, const unsigned short* __restrict__ BT2b,
    const float* __restrict__ bias2f, const float* __restrict__ bias2b,
    const float* __restrict__ att_w,           // [512]
    float* __restrict__ scores,                // [2][4][N] (dir-major)
    int N, int Npad) {
    __shared__ char shx[64 * 128 * 2];           // 16KB: xls during GEMM, sc_ld after
    __shared__ unsigned short hbuf[2][64 * 256]; // 2x32KB h dbuf, swizzled
    unsigned short* xls = (unsigned short*)shx;
    float* sc_ld = (float*)shx;                  // [8][64]

    const int tid = threadIdx.x;
    const int wid = tid >> 6, lane = tid & 63;
    const int l15 = lane & 15, l4 = lane >> 4;
    const int rs = l15 & 7;
    const int m0 = blockIdx.x * 64;
    const int loff = (l15 * 4 + l4) * 8;         // frag lane offset (shorts)
    const bool hi = (l15 & 8) != 0;
    const int dir = blockIdx.y;

    float scl[4] = {0.f, 0.f, 0.f, 0.f};         // meaningful for tid<64

    const unsigned short* BT2 = dir ? BT2b : BT2f;
    const float* bias2 = dir ? bias2b : bias2f;
    const float* attw = att_w + dir * 256;
    for (int i = tid; i < 2048; i += 512) ((uint4*)hbuf[0])[i] = make_uint4(0, 0, 0, 0);
    __syncthreads();
    unsigned short* hcur = hbuf[0];
    unsigned short* hnxt = hbuf[1];
    float c0[4][2], c1[4][2], c2[4][2], c3[4][2];
#pragma unroll
    for (int a = 0; a < 4; ++a) {
        c0[a][0] = 0.f; c0[a][1] = 0.f; c1[a][0] = 0.f; c1[a][1] = 0.f;
        c2[a][0] = 0.f; c2[a][1] = 0.f; c3[a][0] = 0.f; c3[a][1] = 0.f;
    }

#pragma unroll 1
    for (int t = 0; t < 4; ++t) {
        const int lyr = dir ? (3 - t) : t;
        // stage xls (pre-swizzled global source -> linear LDS dest)
        {
            const unsigned short* xl = xs + (size_t)lyr * Npad * 128;
#pragma unroll
            for (int i = 0; i < 2; ++i) {
                int chunk = wid * 2 + i;
                int row = chunk * 4 + l4;
                gld_lds16(xl + (size_t)(m0 + row) * 128 + ((l15 ^ (row & 7)) << 3),
                          xls + chunk * 512);
            }
        }
        __syncthreads();   // B1: xls ready; h(t-1) visible

        float scA[4], scB[4];
#pragma unroll
        for (int a = 0; a < 4; ++a) { scA[a] = 0.f; scB[a] = 0.f; }

#define DO_PASS(P, cp)                                                               \
        {                                                                            \
            const int G = wid * 4 + (P);                                             \
            f32x4 acc[4][2];                                                         \
            _Pragma("unroll")                                                        \
            for (int a = 0; a < 4; ++a) {                                            \
                acc[a][0] = (f32x4){0.f, 0.f, 0.f, 0.f};                             \
                acc[a][1] = (f32x4){0.f, 0.f, 0.f, 0.f};                             \
            }                                                                        \
            const unsigned short* bpp = BT2 + (size_t)G * 12288 + loff;              \
            _Pragma("unroll 1")                                                      \
            for (int ks = 0; ks < 4; ++ks) {                                         \
                bf16x8 bv0 = *(const bf16x8*)(bpp + (ks * 2 + 0) * 512);             \
                bf16x8 bv1 = *(const bf16x8*)(bpp + (ks * 2 + 1) * 512);             \
                _Pragma("unroll")                                                    \
                for (int mi = 0; mi < 4; ++mi) {                                     \
                    bf16x8 av = *(const bf16x8*)(xls + (mi * 16 + l15) * 128 +       \
                                                 (((ks * 4 + l4) ^ rs) << 3));       \
                    acc[mi][0] = __builtin_amdgcn_mfma_f32_16x16x32_bf16(av, bv0, acc[mi][0], 0, 0, 0); \
                    acc[mi][1] = __builtin_amdgcn_mfma_f32_16x16x32_bf16(av, bv1, acc[mi][1], 0, 0, 0); \
                }                                                                    \
            }                                                                        \
            _Pragma("unroll 1")                                                      \
            for (int ks = 4; ks < 12; ++ks) {                                        \
                bf16x8 bv0 = *(const bf16x8*)(bpp + (ks * 2 + 0) * 512);             \
                bf16x8 bv1 = *(const bf16x8*)(bpp + (ks * 2 + 1) * 512);             \
                _Pragma("unroll")                                                    \
                for (int mi = 0; mi < 4; ++mi) {                                     \
                    bf16x8 av = *(const bf16x8*)(hcur + (mi * 16 + l15) * 256 +      \
                                                 ((((ks - 4) * 4 + l4) ^ rs) << 3)); \
                    acc[mi][0] = __builtin_amdgcn_mfma_f32_16x16x32_bf16(av, bv0, acc[mi][0], 0, 0, 0); \
                    acc[mi][1] = __builtin_amdgcn_mfma_f32_16x16x32_bf16(av, bv1, acc[mi][1], 0, 0, 0); \
                }                                                                    \
            }                                                                        \
            const float bi0 = bias2[G * 32 + l15];                                   \
            const float bi1 = bias2[G * 32 + 16 + l15];                              \
            const float aw = attw[G * 8 + (l15 & 7)];                                \
            _Pragma("unroll")                                                        \
            for (int mi = 0; mi < 4; ++mi) {                                         \
                float a00 = acc[mi][0][0] + bi0, a01 = acc[mi][0][1] + bi0;          \
                float a02 = acc[mi][0][2] + bi0, a03 = acc[mi][0][3] + bi0;          \
                float a10 = acc[mi][1][0] + bi1, a11 = acc[mi][1][1] + bi1;          \
                float a12 = acc[mi][1][2] + bi1, a13 = acc[mi][1][3] + bi1;          \
                float r0 = __shfl_xor(hi ? a00 : a02, 8);                            \
                float r1 = __shfl_xor(hi ? a01 : a03, 8);                            \
                float r2 = __shfl_xor(hi ? a10 : a12, 8);                            \
                float r3 = __shfl_xor(hi ? a11 : a13, 8);                            \
                float iA = hi ? r0  : a00,  fA = hi ? a02 : r0;                      \
                float gA = hi ? r2  : a10,  oA = hi ? a12 : r2;                      \
                float iB = hi ? r1  : a01,  fB = hi ? a03 : r1;                      \
                float gB = hi ? r3  : a11,  oB = hi ? a13 : r3;                      \
                const int rA = mi * 16 + l4 * 4 + (hi ? 2 : 0);                      \
                {                                                                    \
                    float gi = fsig(iA), gf = fsig(fA), gg = ftanh(gA), go = fsig(oA); \
                    float cc = fmaf(gf, cp[mi][0], gi * gg);                         \
                    cp[mi][0] = cc;                                                  \
                    float hn = go * ftanh(cc);                                       \
                    scA[mi] = fmaf(hn, aw, scA[mi]);                                 \
                    *(unsigned short*)((char*)hnxt + rA * 512 +                      \
                                       ((G ^ (rA & 7)) << 4) + (l15 & 7) * 2) = f2bf(hn); \
                }                                                                    \
                {                                                                    \
                    const int rB = rA + 1;                                           \
                    float gi = fsig(iB), gf = fsig(fB), gg = ftanh(gB), go = fsig(oB); \
                    float cc = fmaf(gf, cp[mi][1], gi * gg);                         \
                    cp[mi][1] = cc;                                                  \
                    float hn = go * ftanh(cc);                                       \
                    scB[mi] = fmaf(hn, aw, scB[mi]);                                 \
                    *(unsigned short*)((char*)hnxt + rB * 512 +                      \
                                       ((G ^ (rB & 7)) << 4) + (l15 & 7) * 2) = f2bf(hn); \
                }                                                                    \
            }                                                                        \
        }

        DO_PASS(0, c0)
        DO_PASS(1, c1)
        DO_PASS(2, c2)
        DO_PASS(3, c3)
#undef DO_PASS

        __syncthreads();   // B2: all xls/h(t-1) reads + hnxt writes done
        // publish per-row score partials into sc_ld (aliases xls - safe now)
#pragma unroll
        for (int mi = 0; mi < 4; ++mi) {
            float sA = scA[mi], sB = scB[mi];
            sA += __shfl_xor(sA, 1); sA += __shfl_xor(sA, 2); sA += __shfl_xor(sA, 4);
            sB += __shfl_xor(sB, 1); sB += __shfl_xor(sB, 2); sB += __shfl_xor(sB, 4);
            if ((l15 & 7) == 0) {
                int row = mi * 16 + l4 * 4 + (hi ? 2 : 0);
                sc_ld[wid * 64 + row] = sA;
                sc_ld[wid * 64 + row + 1] = sB;
            }
        }
        __syncthreads();   // B3: sc visible
        if (tid < 64) {
            float s = 0.f;
#pragma unroll
            for (int w = 0; w < 8; ++w) s += sc_ld[w * 64 + tid];
#pragma unroll
            for (int l = 0; l < 4; ++l) scl[l] += (l == lyr) ? s : 0.f;
        }
        __syncthreads();   // B4: consumption done -> shx free for next staging
        unsigned short* tmp = hcur; hcur = hnxt; hnxt = tmp;
    }
    if (tid < 64) {
        int n = m0 + tid;
        if (n < N) {
            float* scout = scores + (size_t)dir * 4 * N;
#pragma unroll
            for (int l = 0; l < 4; ++l) scout[(size_t)l * N + n] = scl[l];
        }
    }
}

// ---------------- JK pooling + final predictor ----------------

__global__ __launch_bounds__(256) void k_jk(const float* __restrict__ sc, const unsigned short* __restrict__ xs,
                                            unsigned short* __restrict__ jk, int N, int Npad) {
    int gw = (blockIdx.x * 256 + threadIdx.x) >> 6;
    if (gw >= N) return;
    int lane = threadIdx.x & 63;
    const float* scb = sc + (size_t)4 * N;
    float s0 = sc[gw] + scb[gw];
    float s1 = sc[N + gw] + scb[N + gw];
    float s2 = sc[2 * N + gw] + scb[2 * N + gw];
    float s3 = sc[3 * N + gw] + scb[3 * N + gw];
    float m = fmaxf(fmaxf(s0, s1), fmaxf(s2, s3));
    float e0 = __expf(s0 - m), e1 = __expf(s1 - m), e2 = __expf(s2 - m), e3 = __expf(s3 - m);
    float inv = 1.f / (e0 + e1 + e2 + e3);
    float a0 = e0 * inv, a1 = e1 * inv, a2 = e2 * inv, a3 = e3 * inv;
    size_t stride = (size_t)Npad * 128;
    const unsigned short* p = xs + (size_t)gw * 128 + lane * 2;
    ushort2 v0 = *(const ushort2*)p;
    ushort2 v1 = *(const ushort2*)(p + stride);
    ushort2 v2 = *(const ushort2*)(p + 2 * stride);
    ushort2 v3 = *(const ushort2*)(p + 3 * stride);
    float r0 = a0 * bf2f(v0.x) + a1 * bf2f(v1.x) + a2 * bf2f(v2.x) + a3 * bf2f(v3.x);
    float r1 = a0 * bf2f(v0.y) + a1 * bf2f(v1.y) + a2 * bf2f(v2.y) + a3 * bf2f(v3.y);
    *(ushort2*)&jk[(size_t)gw * 128 + lane * 2] = make_ushort2(f2bf(r0), f2bf(r1));
}

__global__ __launch_bounds__(256) void k_final(const unsigned short* __restrict__ z1, const float* __restrict__ bnst,
                                               const float* __restrict__ w2, const float* __restrict__ b2,
                                               float* __restrict__ out, int EL) {
    int e = (blockIdx.x * 256 + threadIdx.x) >> 6;
    if (e >= EL) return;
    int lane = threadIdx.x & 63;
    ushort2 z = *(const ushort2*)&z1[(size_t)e * 128 + lane * 2];
    int c0 = lane * 2;
    float y0 = bf2f(z.x) * bnst[c0] + bnst[128 + c0];
    float y1 = bf2f(z.y) * bnst[c0 + 1] + bnst[128 + c0 + 1];
    float p = y0 * w2[c0] + y1 * w2[c0 + 1];
#pragma unroll
    for (int off = 32; off; off >>= 1) p += __shfl_xor(p, off);
    if (lane == 0) out[e] = 1.f / (1.f + __expf(-(p + b2[0])));
}

// ---------------- host ----------------

extern "C" void kernel_launch(void* const* d_in, const int* in_sizes, int n_in,
                              void* d_out, int out_size, void* d_ws, size_t ws_size,
                              hipStream_t stream) {
    const int* ei      = (const int*)d_in[0];
    const float* x     = (const float*)d_in[1];
    const int* eli     = (const int*)d_in[2];
    const float* gcn_w = (const float*)d_in[3];
    const float* gcn_b = (const float*)d_in[4];
    const float* sg_w  = (const float*)d_in[5];
    const float* sg_b  = (const float*)d_in[6];
    const float* bn_g  = (const float*)d_in[7];
    const float* bn_b  = (const float*)d_in[8];
    const float* w_ih_f = (const float*)d_in[9];
    const float* w_hh_f = (const float*)d_in[10];
    const float* b_ih_f = (const float*)d_in[11];
    const float* b_hh_f = (const float*)d_in[12];
    const float* w_ih_b = (const float*)d_in[13];
    const float* w_hh_b = (const float*)d_in[14];
    const float* b_ih_b = (const float*)d_in[15];
    const float* b_hh_b = (const float*)d_in[16];
    const float* att_w = (const float*)d_in[17];
    // d_in[18] = att_b: softmax over layers is shift-invariant -> unused
    const float* p1_w  = (const float*)d_in[19];
    const float* p1_b  = (const float*)d_in[20];
    const float* pbn_g = (const float*)d_in[21];
    const float* pbn_b = (const float*)d_in[22];
    const float* p2_w  = (const float*)d_in[23];
    const float* p2_b  = (const float*)d_in[24];

    const int E = in_sizes[0] / 2;
    const int N = in_sizes[1] / 128;
    const int EL = in_sizes[2] / 2;
    const int Npad = CDIV(N, 128) * 128;
    const int ELpad = CDIV(EL, 128) * 128;
    const size_t NB128 = (size_t)Npad * 128 * 2;

    char* wsp = (char*)d_ws;
    size_t off = 0;
    auto A = [&](size_t b) -> char* {
        char* p = wsp + off;
        off = (off + b + 255) & ~(size_t)255;
        return p;
    };
    // ---- persistent ----
    int* degi = (int*)A((size_t)N * 4);
    float* dinv = (float*)A((size_t)N * 4);
    int* rowp = (int*)A((size_t)N * 4);
    int* curs = (int*)A((size_t)N * 4);
    int* bsum = (int*)A(256 * 4);
    unsigned short* gT   = (unsigned short*)A(128 * 128 * 2);
    unsigned short* sgT  = (unsigned short*)A(3 * 128 * 128 * 2);
    unsigned short* p1T  = (unsigned short*)A(128 * 256 * 2);
    unsigned short* BTf  = (unsigned short*)A(1024 * 384 * 2);
    unsigned short* BTb  = (unsigned short*)A(1024 * 384 * 2);
    float* biasf = (float*)A(1024 * 4);
    float* biasb = (float*)A(1024 * 4);
    float* part = (float*)A(256 * 256 * 4);
    float* bnst = (float*)A(256 * 4);
    float* scores = (float*)A((size_t)8 * N * 4);   // [2][4][N]
    unsigned short* xs = (unsigned short*)A(NB128 * 4);
    // ---- phase-aliased arena ----
    const size_t arena0 = off;
    int* csr = (int*)A((size_t)E * 4);
    unsigned short* xb   = (unsigned short*)A(NB128);
    unsigned short* bufA = (unsigned short*)A(NB128);
    unsigned short* bufB = (unsigned short*)A(NB128);
    const size_t convEnd = off;
    off = arena0;
    unsigned short* jk = (unsigned short*)A((size_t)N * 128 * 2);
    unsigned short* z1 = (unsigned short*)A((size_t)ELpad * 128 * 2);
    const size_t predEnd = off;
    if (convEnd > ws_size || predEnd > ws_size) return;  // workspace too small

    // --- degree, dinv, CSR ---
    k_zero4<<<CDIV((size_t)N * 4, 16 * 256), 256, 0, stream>>>((uint4*)degi, CDIV((size_t)N * 4, 16));
    k_deg<<<CDIV(E, 256), 256, 0, stream>>>(ei, degi, E);
    k_dinv<<<CDIV(N, 256), 256, 0, stream>>>(degi, dinv, N);
    int nb = CDIV(N, SCAN_B);
    k_scan1<<<nb, 256, 0, stream>>>(degi, rowp, bsum, N);
    k_scan2<<<1, 64, 0, stream>>>(bsum, nb);
    k_scan3<<<CDIV(N, 256), 256, 0, stream>>>(rowp, curs, bsum, N);
    k_fill<<<CDIV(E, 256), 256, 0, stream>>>(ei, curs, csr, E);

    // --- convert + weight packs ---
    k_xconv<<<CDIV(Npad * 64, 256), 256, 0, stream>>>(x, xb, N, Npad);
    k_packT<<<CDIV(128 * 128, 256), 256, 0, stream>>>(gcn_w, gT, 128, 128);
    for (int i = 0; i < 3; ++i)
        k_packT<<<CDIV(128 * 128, 256), 256, 0, stream>>>(sg_w + (size_t)i * 128 * 128, sgT + (size_t)i * 128 * 128, 128, 128);
    k_packT<<<CDIV(256 * 128, 256), 256, 0, stream>>>(p1_w, p1T, 256, 128);
    k_packlstm4<<<CDIV(1024 * 384, 256), 256, 0, stream>>>(w_ih_f, w_hh_f, BTf);
    k_packlstm4<<<CDIV(1024 * 384, 256), 256, 0, stream>>>(w_ih_b, w_hh_b, BTb);
    k_packbias4<<<4, 256, 0, stream>>>(b_ih_f, b_hh_f, biasf);
    k_packbias4<<<4, 256, 0, stream>>>(b_ih_b, b_hh_b, biasb);

    const int MT = Npad / 128;
    // --- GCNConv: lin -> prop(+bias,relu) -> BN ---
    k_gemm<0><<<MT, 256, 32768, stream>>>(xb, 128, 128, nullptr, 0, 128, gT, 128,
                                          nullptr, nullptr, 0, nullptr, 0, bufA, 128, 1);
    k_prop<<<CDIV(Npad * 8, 256), 256, 0, stream>>>(bufA, rowp, degi, csr, dinv, gcn_b, 1, N, Npad, bufB);
    k_stats<<<256, 256, 0, stream>>>(bufB, N, part);
    k_bnfinal<<<1, 128, 0, stream>>>(part, 256, (float)N, bn_g, bn_b, bnst);
    k_apply<<<CDIV(Npad * 64, 256), 256, 0, stream>>>(bufB, bnst, xs, N, Npad);

    // --- SGConv stack: prop -> lin(+bias[,relu]) [-> BN] ---
    for (int i = 0; i < 3; ++i) {
        k_prop<<<CDIV(Npad * 8, 256), 256, 0, stream>>>(xs + (size_t)i * Npad * 128, rowp, degi, csr, dinv,
                                                        nullptr, 0, N, Npad, bufA);
        unsigned short* dst = (i < 2) ? bufB : xs + (size_t)3 * Npad * 128;
        k_gemm<0><<<MT, 256, 32768, stream>>>(bufA, 128, 128, nullptr, 0, 128,
                                              sgT + (size_t)i * 128 * 128, 128,
                                              nullptr, nullptr, 0, sg_b + i * 128, (i < 2) ? 1 : 0, dst, 128, 1);
        if (i < 2) {
            k_stats<<<256, 256, 0, stream>>>(bufB, N, part);
            k_bnfinal<<<1, 128, 0, stream>>>(part, 256, (float)N, bn_g, bn_b, bnst);
            k_apply<<<CDIV(Npad * 64, 256), 256, 0, stream>>>(bufB, bnst, xs + (size_t)(i + 1) * Npad * 128, N, Npad);
        }
    }

    // --- fused bidirectional LSTM + attention scores (dir = blockIdx.y) ---
    k_lstm_fused<<<dim3(Npad / 64, 2), 512, 0, stream>>>(xs, BTf, BTb, biasf, biasb, att_w, scores, N, Npad);

    // --- JK pooling ---
    k_jk<<<CDIV(N * 64, 256), 256, 0, stream>>>(scores, xs, jk, N, Npad);

    // --- edge predictor ---
    const int MTe = ELpad / 128;
    k_gemm<1><<<MTe, 256, 32768, stream>>>(jk, 128, 128, nullptr, 0, 256, p1T, 256,
                                           eli, eli + EL, EL, p1_b, 1, z1, 128, 1);
    k_stats<<<256, 256, 0, stream>>>(z1, EL, part);
    k_bnfinal<<<1, 128, 0, stream>>>(part, 256, (float)EL, pbn_g, pbn_b, bnst);
    k_final<<<CDIV(EL * 64, 256), 256, 0, stream>>>(z1, bnst, p2_w, p2_b, (float*)d_out, EL);
    (void)n_in; (void)out_size;
}